// Round 5
// baseline (327.545 us; speedup 1.0000x reference)
//
#include <hip/hip_runtime.h>

#define TB 256

// Wave-synchronous fence: DS ops complete in order within a wave (ISA
// guarantee); this only stops the COMPILER from reordering/caching LDS.
#define WAVE_SYNC() do { asm volatile("" ::: "memory"); \
                         __builtin_amdgcn_wave_barrier(); \
                         asm volatile("" ::: "memory"); } while (0)

// ---------------- LDS layout (float offsets), total 9600 floats = 38.4 KB ----
// Weight region (restaged per layer, shared by both samples):
#define WQKV 0        // 192 rows x 20 (16 used)
#define BQKV 3840     // 192
#define WOUT 4032     // 16 rows x 68 (64 used)
#define BOUT 5120     // 16
#define WM1  5136     // 32 rows x 20
#define BM1  5776     // 32
#define WM2  5808     // 16 rows x 36 (32 used)
#define BM2  6384     // 16
#define LN1G 6400
#define LN1B 6416
#define LN2G 6432
#define LN2B 6448
#define WEND 6464
// Per-sample scratch (s = 0,1): base = WEND + s*SSTR
#define SSTR 1568
#define SH1  0        // 6 x 20
#define SQKV 128      // 6 x 196 (q at +0 -- reused as O after attention, k +64, v +128)
#define SMHS 1312     // 6 x 36
#define LDS_TOT (WEND + 2*SSTR)   // 9600
// Frontend aliases (per sample, dead before first staging): base = s*FSTR
#define FSTR 3664
#define FXSP  0       // 16 x 196 zero-padded
#define FPOOL 3136    // 16 x 28
#define FTOK  3584    // 80

__device__ __forceinline__ float ln_norm16(float z, float g, float bb) {
    float s = z, q = z * z;
    #pragma unroll
    for (int off = 8; off >= 1; off >>= 1) {
        s += __shfl_xor(s, off, 16);
        q += __shfl_xor(q, off, 16);
    }
    float mean = s * 0.0625f;
    float var  = q * 0.0625f - mean * mean;
    return (z - mean) * rsqrtf(var + 1e-5f) * g + bb;
}

__device__ __forceinline__ float gelu_exact(float a) {
    float xa = fabsf(a) * 0.70710678118654752f;
    float tt = 1.f / (1.f + 0.3275911f * xa);
    float poly = tt * (0.254829592f + tt * (-0.284496736f + tt * (1.421413741f
               + tt * (-1.453152027f + tt * 1.061405429f))));
    float erfv = 1.f - poly * __expf(-xa * xa);
    erfv = a >= 0.f ? erfv : -erfv;
    return 0.5f * a * (1.f + erfv);
}

__device__ __forceinline__ float dot16(const float* h, float4 w0, float4 w1,
                                       float4 w2, float4 w3) {
    return h[0]*w0.x + h[1]*w0.y + h[2]*w0.z + h[3]*w0.w
         + h[4]*w1.x + h[5]*w1.y + h[6]*w1.z + h[7]*w1.w
         + h[8]*w2.x + h[9]*w2.y + h[10]*w2.z + h[11]*w2.w
         + h[12]*w3.x + h[13]*w3.y + h[14]*w3.z + h[15]*w3.w;
}

// (256,4): 4 waves/EU -> 4 blocks/CU -> 16 waves/CU; VGPR cap 128 (round 4's
// identical inner structure measured 124, so no spills expected).
extern "C" __global__ __launch_bounds__(TB, 4)
void eegnet_vit_fused(
    const float* __restrict__ x,
    const float* __restrict__ conv_t_w, const float* __restrict__ conv_t_b,
    const float* __restrict__ bn1_g, const float* __restrict__ bn1_b,
    const float* __restrict__ bn1_m, const float* __restrict__ bn1_v,
    const float* __restrict__ conv_s_w, const float* __restrict__ conv_s_b,
    const float* __restrict__ bn2_g, const float* __restrict__ bn2_b,
    const float* __restrict__ bn2_m, const float* __restrict__ bn2_v,
    const float* __restrict__ proj_w, const float* __restrict__ proj_b,
    const float* __restrict__ cls_token, const float* __restrict__ pe,
    const float* __restrict__ qkv_w, const float* __restrict__ qkv_b,
    const float* __restrict__ out_w, const float* __restrict__ out_b,
    const float* __restrict__ ln1_g, const float* __restrict__ ln1_b,
    const float* __restrict__ ln2_g, const float* __restrict__ ln2_b,
    const float* __restrict__ mlp_w1, const float* __restrict__ mlp_b1,
    const float* __restrict__ mlp_w2, const float* __restrict__ mlp_b2,
    const float* __restrict__ head_ln_g, const float* __restrict__ head_ln_b,
    const float* __restrict__ head_w, const float* __restrict__ head_b,
    float* __restrict__ out)
{
    __shared__ __align__(16) float sm[LDS_TOT];
    const int tid = threadIdx.x;
    const int ss  = tid >> 7;              // sample within block (0/1)
    const int u   = tid & 127;             // index within the sample's wave pair
    const int b2  = blockIdx.x * 2 + ss;   // global sample id
    float* smf = sm + ss * FSTR;           // frontend base for this sample

    // ---------- zero ONLY the pad zones of XSP: per row [0,32) and [157,196) ----
    for (int i = u; i < 16 * 71; i += 128) {
        int row = i / 71, k = i - row * 71;
        int off = (k < 32) ? k : (k + 125);
        smf[FXSP + row * 196 + off] = 0.f;
    }

    // ---------- stage 1: spatial conv, one t-column per lane ----------
    {
        const float* xb = x + (size_t)b2 * 8000;
        const int t = min(u, 124);
        float a0[16];
        #pragma unroll
        for (int o = 0; o < 16; ++o) a0[o] = 0.f;
        #pragma unroll 8
        for (int c = 0; c < 64; ++c) {
            float xv = xb[c * 125 + t];
            #pragma unroll
            for (int o = 0; o < 16; ++o)
                a0[o] += conv_s_w[o * 64 + c] * xv;    // wave-uniform -> s_load
        }
        if (u < 125) {
            #pragma unroll
            for (int o = 0; o < 16; ++o)
                smf[FXSP + o * 196 + 32 + t] = a0[o];
        }
    }

    // ---------- fused BN constants + temporal taps (per-lane, oo = u&15) --------
    const int oo = u & 15, qg = u >> 4, gg = oo >> 1;   // qg in 0..7
    float sa, cc;
    {
        float s1 = bn1_g[gg] * rsqrtf(bn1_v[gg] + 1e-5f);
        float b1 = (conv_t_b[gg] - bn1_m[gg]) * s1 + bn1_b[gg];
        float s2 = bn2_g[oo] * rsqrtf(bn2_v[oo] + 1e-5f);
        float ssum = 0.f;
        const float4* csw = reinterpret_cast<const float4*>(conv_s_w + oo * 64);
        #pragma unroll
        for (int i = 0; i < 16; ++i) {
            float4 v = csw[i];
            ssum += v.x + v.y + v.z + v.w;
        }
        sa = s1 * s2;
        cc = (b1 * ssum + conv_s_b[oo] - bn2_m[oo]) * s2 + bn2_b[oo];
    }
    float wt[63];
    #pragma unroll
    for (int k = 0; k < 63; ++k) wt[k] = conv_t_w[gg * 63 + k];

    __syncthreads();   // XSP complete

    // ---------- stage 2: temporal conv + BN + ELU + avg-pool ----------
    #pragma unroll 1
    for (int jj = 0; jj < 4; ++jj) {
        int j = qg + 8 * jj;
        if (j < 25) {
            int base = FXSP + oo * 196 + 5 * j + 1;
            float acc5[5] = {0.f, 0.f, 0.f, 0.f, 0.f};
            #pragma unroll
            for (int m = 0; m < 67; ++m) {
                float xv = smf[base + m];
                #pragma unroll
                for (int uu = 0; uu < 5; ++uu)
                    if (uu <= m && m - uu <= 62) acc5[uu] += wt[m - uu] * xv;
            }
            float psum = 0.f;
            #pragma unroll
            for (int uu = 0; uu < 5; ++uu) {
                float v = acc5[uu] * sa + cc;
                psum += (v > 0.f) ? v : (__expf(v) - 1.f);
            }
            smf[FPOOL + oo * 28 + j] = psum * 0.2f;
        }
    }

    __syncthreads();   // POOL complete

    // ---------- stage 3: token projection ----------
    if (u < 80) {
        int p = u >> 4, dd = u & 15;
        float acc = proj_b[dd];
        const float4* wp = reinterpret_cast<const float4*>(proj_w + dd * 80);
        #pragma unroll
        for (int i = 0; i < 20; ++i) {
            float4 w4 = wp[i];
            acc += w4.x * smf[FPOOL + ((4*i+0)/5) * 28 + p * 5 + ((4*i+0)%5)];
            acc += w4.y * smf[FPOOL + ((4*i+1)/5) * 28 + p * 5 + ((4*i+1)%5)];
            acc += w4.z * smf[FPOOL + ((4*i+2)/5) * 28 + p * 5 + ((4*i+2)%5)];
            acc += w4.w * smf[FPOOL + ((4*i+3)/5) * 28 + p * 5 + ((4*i+3)%5)];
        }
        smf[FTOK + p * 16 + dd] = acc;
    }

    __syncthreads();   // TOK complete

    // ---------- z init ----------
    const int d16 = u & 15;
    const int t6c = min(qg, 5);            // wave0: tokens 0-3; wave1: 4,5,5,5
    float z = ((t6c == 0) ? cls_token[d16] : smf[FTOK + (t6c - 1) * 16 + d16])
            + pe[t6c * 16 + d16];

    const int sb   = WEND + ss * SSTR;     // scratch base for this sample
    const int wav  = u >> 6;               // wave within the sample pair (0/1)
    const int al   = u & 63;

    // ---------- transformer: 6 layers ----------
    #pragma unroll 1
    for (int li = 0; li < 6; ++li) {
        __syncthreads();   // prev-layer weight/scratch reads done (and z-init)

        // --- stage layer weights into LDS (coalesced float4, all 256 threads) ---
        {
            const float4* s1 = reinterpret_cast<const float4*>(qkv_w + li * 3072);
            #pragma unroll
            for (int it = 0; it < 3; ++it) {
                int i = tid + it * 256;            // 768 float4
                float4 v = s1[i];
                int j = i >> 2, k = (i & 3) << 2;
                *reinterpret_cast<float4*>(&sm[WQKV + j * 20 + k]) = v;
            }
            {
                float4 v = reinterpret_cast<const float4*>(out_w + li * 1024)[tid];
                int j = tid >> 4, k = (tid & 15) << 2;
                *reinterpret_cast<float4*>(&sm[WOUT + j * 68 + k]) = v;
            }
            if (tid < 128) {
                float4 v = reinterpret_cast<const float4*>(mlp_w1 + li * 512)[tid];
                int j = tid >> 2, k = (tid & 3) << 2;
                *reinterpret_cast<float4*>(&sm[WM1 + j * 20 + k]) = v;
            } else {
                int i = tid - 128;
                float4 v = reinterpret_cast<const float4*>(mlp_w2 + li * 512)[i];
                int j = i >> 3, k = (i & 7) << 2;
                *reinterpret_cast<float4*>(&sm[WM2 + j * 36 + k]) = v;
            }
            if (tid < 192) sm[BQKV + tid] = qkv_b[li * 192 + tid];
            else if (tid < 208) sm[BOUT + tid - 192] = out_b[li * 16 + tid - 192];
            else if (tid < 240) sm[BM1 + tid - 208]  = mlp_b1[li * 32 + tid - 208];
            else               sm[BM2 + tid - 240]  = mlp_b2[li * 16 + tid - 240];
            if (tid >= 64 && tid < 80)        sm[LN1G + tid - 64]  = ln1_g[li * 16 + tid - 64];
            else if (tid >= 80 && tid < 96)   sm[LN1B + tid - 80]  = ln1_b[li * 16 + tid - 80];
            else if (tid >= 96 && tid < 112)  sm[LN2G + tid - 96]  = ln2_g[li * 16 + tid - 96];
            else if (tid >= 112 && tid < 128) sm[LN2B + tid - 112] = ln2_b[li * 16 + tid - 112];
        }
        __syncthreads();   // weights ready

        // --- LN1 -> H1 (wave-local rows) ---
        sm[sb + SH1 + t6c * 20 + d16] = ln_norm16(z, sm[LN1G + d16], sm[LN1B + d16]);
        WAVE_SYNC();

        float hr[16];
        {
            const float4* pA = reinterpret_cast<const float4*>(&sm[sb + SH1 + t6c * 20]);
            #pragma unroll
            for (int i = 0; i < 4; ++i) {
                float4 va = pA[i];
                hr[4*i+0] = va.x; hr[4*i+1] = va.y; hr[4*i+2] = va.z; hr[4*i+3] = va.w;
            }
        }

        // --- qkv: lane computes cols j = d16+16r for its token (weights from LDS) ---
        #pragma unroll 2
        for (int r = 0; r < 12; ++r) {
            int j = d16 + 16 * r;
            const float4* wp = reinterpret_cast<const float4*>(&sm[WQKV + j * 20]);
            float4 w0 = wp[0], w1_ = wp[1], w2_ = wp[2], w3_ = wp[3];
            sm[sb + SQKV + t6c * 196 + j] = sm[BQKV + j] + dot16(hr, w0, w1_, w2_, w3_);
        }
        __syncthreads();   // QKV ready (cross-wave: K,V of all tokens)

        // --- attention: wave0 -> queries 0-3 (32 lanes), wave1 -> 4,5 (16 lanes) ---
        {
            bool act = (wav == 0) ? (al < 32) : (al < 16);
            if (act) {
                int h  = al & 7;
                int qs = (wav == 0) ? (al >> 3) : 4 + (al >> 3);
                const int qoff = sb + SQKV + qs * 196 + h * 8;
                const float4* qp = reinterpret_cast<const float4*>(&sm[qoff]);
                float4 q0 = qp[0], q1 = qp[1];
                float sc[6];
                #pragma unroll
                for (int t = 0; t < 6; ++t) {
                    const float4* kp = reinterpret_cast<const float4*>(&sm[sb + SQKV + t * 196 + 64 + h * 8]);
                    float4 k0 = kp[0], k1 = kp[1];
                    sc[t] = (q0.x*k0.x + q0.y*k0.y + q0.z*k0.z + q0.w*k0.w
                           + q1.x*k1.x + q1.y*k1.y + q1.z*k1.z + q1.w*k1.w)
                           * 0.35355339059327373f;
                }
                float mx = sc[0];
                #pragma unroll
                for (int t = 1; t < 6; ++t) mx = fmaxf(mx, sc[t]);
                float ssum = 0.f;
                #pragma unroll
                for (int t = 0; t < 6; ++t) { sc[t] = __expf(sc[t] - mx); ssum += sc[t]; }
                float inv = 1.f / ssum;
                float o0=0.f,o1=0.f,o2=0.f,o3=0.f,o4=0.f,o5=0.f,o6=0.f,o7=0.f;
                #pragma unroll
                for (int t = 0; t < 6; ++t) {
                    const float4* vp = reinterpret_cast<const float4*>(&sm[sb + SQKV + t * 196 + 128 + h * 8]);
                    float4 v0 = vp[0], v1 = vp[1];
                    float a = sc[t] * inv;
                    o0 += a*v0.x; o1 += a*v0.y; o2 += a*v0.z; o3 += a*v0.w;
                    o4 += a*v1.x; o5 += a*v1.y; o6 += a*v1.z; o7 += a*v1.w;
                }
                // overwrite own q slot with O (only this lane ever read it)
                *reinterpret_cast<float4*>(&sm[qoff    ]) = float4{o0,o1,o2,o3};
                *reinterpret_cast<float4*>(&sm[qoff + 4]) = float4{o4,o5,o6,o7};
            }
        }
        WAVE_SYNC();   // O rows are wave-local (own wave computed own tokens)

        // --- out projection + residual ---
        {
            const float4* wop = reinterpret_cast<const float4*>(&sm[WOUT + d16 * 68]);
            const float4* oa  = reinterpret_cast<const float4*>(&sm[sb + SQKV + t6c * 196]);
            float acc = sm[BOUT + d16];
            #pragma unroll 4
            for (int i = 0; i < 16; ++i) {
                float4 w = wop[i];
                float4 va = oa[i];
                acc += va.x*w.x + va.y*w.y + va.z*w.z + va.w*w.w;
            }
            z += acc;
        }

        // --- LN2 -> H1 (wave-local) ---
        sm[sb + SH1 + t6c * 20 + d16] = ln_norm16(z, sm[LN2G + d16], sm[LN2B + d16]);
        WAVE_SYNC();
        {
            const float4* pA = reinterpret_cast<const float4*>(&sm[sb + SH1 + t6c * 20]);
            #pragma unroll
            for (int i = 0; i < 4; ++i) {
                float4 va = pA[i];
                hr[4*i+0] = va.x; hr[4*i+1] = va.y; hr[4*i+2] = va.z; hr[4*i+3] = va.w;
            }
        }

        // --- mlp1 + GELU -> MHS (wave-local) ---
        #pragma unroll
        for (int r = 0; r < 2; ++r) {
            int uu = d16 + 16 * r;
            const float4* wp = reinterpret_cast<const float4*>(&sm[WM1 + uu * 20]);
            float4 w0 = wp[0], w1_ = wp[1], w2_ = wp[2], w3_ = wp[3];
            float a = sm[BM1 + uu] + dot16(hr, w0, w1_, w2_, w3_);
            sm[sb + SMHS + t6c * 36 + uu] = gelu_exact(a);
        }
        WAVE_SYNC();

        // --- mlp2 + residual (wave-local MHS read) ---
        {
            const float4* wp = reinterpret_cast<const float4*>(&sm[WM2 + d16 * 36]);
            const float4* mA = reinterpret_cast<const float4*>(&sm[sb + SMHS + t6c * 36]);
            float acc = sm[BM2 + d16];
            #pragma unroll
            for (int i = 0; i < 8; ++i) {
                float4 w = wp[i];
                float4 va = mA[i];
                acc += va.x*w.x + va.y*w.y + va.z*w.z + va.w*w.w;
            }
            z += acc;
        }
        // loop-top __syncthreads orders all cross-wave reads before restaging
    }

    // ---------- head: LN(cls) -> 2-way linear -> softmax ----------
    if (u < 16) {
        float cv = ln_norm16(z, head_ln_g[d16], head_ln_b[d16]);
        float p0 = cv * head_w[d16];
        float p1 = cv * head_w[16 + d16];
        #pragma unroll
        for (int off = 8; off >= 1; off >>= 1) {
            p0 += __shfl_xor(p0, off, 16);
            p1 += __shfl_xor(p1, off, 16);
        }
        if (u == 0) {
            float l0 = p0 + head_b[0], l1 = p1 + head_b[1];
            float mx = fmaxf(l0, l1);
            float e0 = __expf(l0 - mx), e1 = __expf(l1 - mx);
            float inv = 1.f / (e0 + e1);
            out[b2 * 2 + 0] = e0 * inv;
            out[b2 * 2 + 1] = e1 * inv;
        }
    }
}

extern "C" void kernel_launch(void* const* d_in, const int* in_sizes, int n_in,
                              void* d_out, int out_size, void* d_ws, size_t ws_size,
                              hipStream_t stream) {
    (void)n_in; (void)d_ws; (void)ws_size; (void)out_size;
    const float* a0  = (const float*)d_in[0];
    const float* a1  = (const float*)d_in[1];
    const float* a2  = (const float*)d_in[2];
    const float* a3  = (const float*)d_in[3];
    const float* a4  = (const float*)d_in[4];
    const float* a5  = (const float*)d_in[5];
    const float* a6  = (const float*)d_in[6];
    const float* a7  = (const float*)d_in[7];
    const float* a8  = (const float*)d_in[8];
    const float* a9  = (const float*)d_in[9];
    const float* a10 = (const float*)d_in[10];
    const float* a11 = (const float*)d_in[11];
    const float* a12 = (const float*)d_in[12];
    const float* a13 = (const float*)d_in[13];
    const float* a14 = (const float*)d_in[14];
    const float* a15 = (const float*)d_in[15];
    const float* a16 = (const float*)d_in[16];
    const float* a17 = (const float*)d_in[17];
    const float* a18 = (const float*)d_in[18];
    const float* a19 = (const float*)d_in[19];
    const float* a20 = (const float*)d_in[20];
    const float* a21 = (const float*)d_in[21];
    const float* a22 = (const float*)d_in[22];
    const float* a23 = (const float*)d_in[23];
    const float* a24 = (const float*)d_in[24];
    const float* a25 = (const float*)d_in[25];
    const float* a26 = (const float*)d_in[26];
    const float* a27 = (const float*)d_in[27];
    const float* a28 = (const float*)d_in[28];
    const float* a29 = (const float*)d_in[29];
    const float* a30 = (const float*)d_in[30];
    const float* a31 = (const float*)d_in[31];
    const float* a32 = (const float*)d_in[32];

    int Bn = in_sizes[0] / (64 * 125);          // 2048 samples, 2 per block
    eegnet_vit_fused<<<Bn / 2, TB, 0, stream>>>(
        a0, a1, a2, a3, a4, a5, a6, a7, a8, a9, a10, a11, a12, a13, a14, a15, a16,
        a17, a18, a19, a20, a21, a22, a23, a24, a25, a26, a27, a28, a29, a30, a31, a32,
        (float*)d_out);
}

// Round 6
// 248.402 us; speedup vs baseline: 1.3186x; 1.3186x over previous
//
#include <hip/hip_runtime.h>

#define TB 256

// Wave-synchronous fence: DS ops complete in order within a wave (ISA
// guarantee); this only stops the COMPILER from reordering/caching LDS.
#define WAVE_SYNC() do { asm volatile("" ::: "memory"); \
                         __builtin_amdgcn_wave_barrier(); \
                         asm volatile("" ::: "memory"); } while (0)

// ---------------- LDS layout (float offsets), total 9600 floats = 38.4 KB ----
// Weight region (restaged per layer, shared by both samples):
#define WQKV 0        // 192 rows x 20 (16 used)
#define BQKV 3840     // 192
#define WOUT 4032     // 16 rows x 68 (64 used)
#define BOUT 5120     // 16
#define WM1  5136     // 32 rows x 20
#define BM1  5776     // 32
#define WM2  5808     // 16 rows x 36 (32 used)
#define BM2  6384     // 16
#define LN1G 6400
#define LN1B 6416
#define LN2G 6432
#define LN2B 6448
#define WEND 6464
// Per-sample scratch (s = 0,1): base = WEND + s*SSTR
#define SSTR 1568
#define SH1  0        // 6 x 20
#define SQKV 128      // 6 x 196 (q at +0 -- reused as O after attention, k +64, v +128)
#define SMHS 1312     // 6 x 36
#define LDS_TOT (WEND + 2*SSTR)   // 9600
// Frontend aliases (per sample, dead before first staging): base = s*FSTR
#define FSTR 3664
#define FXSP  0       // 16 x 196 zero-padded
#define FPOOL 3136    // 16 x 28
#define FTOK  3584    // 80

__device__ __forceinline__ float ln_norm16(float z, float g, float bb) {
    float s = z, q = z * z;
    #pragma unroll
    for (int off = 8; off >= 1; off >>= 1) {
        s += __shfl_xor(s, off, 16);
        q += __shfl_xor(q, off, 16);
    }
    float mean = s * 0.0625f;
    float var  = q * 0.0625f - mean * mean;
    return (z - mean) * rsqrtf(var + 1e-5f) * g + bb;
}

__device__ __forceinline__ float gelu_exact(float a) {
    float xa = fabsf(a) * 0.70710678118654752f;
    float tt = 1.f / (1.f + 0.3275911f * xa);
    float poly = tt * (0.254829592f + tt * (-0.284496736f + tt * (1.421413741f
               + tt * (-1.453152027f + tt * 1.061405429f))));
    float erfv = 1.f - poly * __expf(-xa * xa);
    erfv = a >= 0.f ? erfv : -erfv;
    return 0.5f * a * (1.f + erfv);
}

__device__ __forceinline__ float dot16(const float* h, float4 w0, float4 w1,
                                       float4 w2, float4 w3) {
    return h[0]*w0.x + h[1]*w0.y + h[2]*w0.z + h[3]*w0.w
         + h[4]*w1.x + h[5]*w1.y + h[6]*w1.z + h[7]*w1.w
         + h[8]*w2.x + h[9]*w2.y + h[10]*w2.z + h[11]*w2.w
         + h[12]*w3.x + h[13]*w3.y + h[14]*w3.z + h[15]*w3.w;
}

// (256,2): measured-safe VGPR budget. Empirical on this compiler:
// arg=4 -> 64-VGPR cap -> wt[63] spills -> ~150 MB scratch traffic (rounds 3&5);
// arg=2 -> ~124 VGPR, no spills (round 4). HW still fits 4 waves/SIMD at 124
// VGPR (512-reg pool) and 4 blocks/CU at 38.4 KB LDS -> 16 waves/CU.
extern "C" __global__ __launch_bounds__(TB, 2)
void eegnet_vit_fused(
    const float* __restrict__ x,
    const float* __restrict__ conv_t_w, const float* __restrict__ conv_t_b,
    const float* __restrict__ bn1_g, const float* __restrict__ bn1_b,
    const float* __restrict__ bn1_m, const float* __restrict__ bn1_v,
    const float* __restrict__ conv_s_w, const float* __restrict__ conv_s_b,
    const float* __restrict__ bn2_g, const float* __restrict__ bn2_b,
    const float* __restrict__ bn2_m, const float* __restrict__ bn2_v,
    const float* __restrict__ proj_w, const float* __restrict__ proj_b,
    const float* __restrict__ cls_token, const float* __restrict__ pe,
    const float* __restrict__ qkv_w, const float* __restrict__ qkv_b,
    const float* __restrict__ out_w, const float* __restrict__ out_b,
    const float* __restrict__ ln1_g, const float* __restrict__ ln1_b,
    const float* __restrict__ ln2_g, const float* __restrict__ ln2_b,
    const float* __restrict__ mlp_w1, const float* __restrict__ mlp_b1,
    const float* __restrict__ mlp_w2, const float* __restrict__ mlp_b2,
    const float* __restrict__ head_ln_g, const float* __restrict__ head_ln_b,
    const float* __restrict__ head_w, const float* __restrict__ head_b,
    float* __restrict__ out)
{
    __shared__ __align__(16) float sm[LDS_TOT];
    const int tid = threadIdx.x;
    const int ss  = tid >> 7;              // sample within block (0/1)
    const int u   = tid & 127;             // index within the sample's wave pair
    const int b2  = blockIdx.x * 2 + ss;   // global sample id
    float* smf = sm + ss * FSTR;           // frontend base for this sample

    // ---------- zero ONLY the pad zones of XSP: per row [0,32) and [157,196) ----
    for (int i = u; i < 16 * 71; i += 128) {
        int row = i / 71, k = i - row * 71;
        int off = (k < 32) ? k : (k + 125);
        smf[FXSP + row * 196 + off] = 0.f;
    }

    // ---------- stage 1: spatial conv, one t-column per lane ----------
    {
        const float* xb = x + (size_t)b2 * 8000;
        const int t = min(u, 124);
        float a0[16];
        #pragma unroll
        for (int o = 0; o < 16; ++o) a0[o] = 0.f;
        #pragma unroll 8
        for (int c = 0; c < 64; ++c) {
            float xv = xb[c * 125 + t];
            #pragma unroll
            for (int o = 0; o < 16; ++o)
                a0[o] += conv_s_w[o * 64 + c] * xv;    // wave-uniform -> s_load
        }
        if (u < 125) {
            #pragma unroll
            for (int o = 0; o < 16; ++o)
                smf[FXSP + o * 196 + 32 + t] = a0[o];
        }
    }

    // ---------- fused BN constants + temporal taps (per-lane, oo = u&15) --------
    const int oo = u & 15, qg = u >> 4, gg = oo >> 1;   // qg in 0..7
    float sa, cc;
    {
        float s1 = bn1_g[gg] * rsqrtf(bn1_v[gg] + 1e-5f);
        float b1 = (conv_t_b[gg] - bn1_m[gg]) * s1 + bn1_b[gg];
        float s2 = bn2_g[oo] * rsqrtf(bn2_v[oo] + 1e-5f);
        float ssum = 0.f;
        const float4* csw = reinterpret_cast<const float4*>(conv_s_w + oo * 64);
        #pragma unroll
        for (int i = 0; i < 16; ++i) {
            float4 v = csw[i];
            ssum += v.x + v.y + v.z + v.w;
        }
        sa = s1 * s2;
        cc = (b1 * ssum + conv_s_b[oo] - bn2_m[oo]) * s2 + bn2_b[oo];
    }
    float wt[63];
    #pragma unroll
    for (int k = 0; k < 63; ++k) wt[k] = conv_t_w[gg * 63 + k];

    __syncthreads();   // XSP complete

    // ---------- stage 2: temporal conv + BN + ELU + avg-pool ----------
    #pragma unroll 1
    for (int jj = 0; jj < 4; ++jj) {
        int j = qg + 8 * jj;
        if (j < 25) {
            int base = FXSP + oo * 196 + 5 * j + 1;
            float acc5[5] = {0.f, 0.f, 0.f, 0.f, 0.f};
            #pragma unroll
            for (int m = 0; m < 67; ++m) {
                float xv = smf[base + m];
                #pragma unroll
                for (int uu = 0; uu < 5; ++uu)
                    if (uu <= m && m - uu <= 62) acc5[uu] += wt[m - uu] * xv;
            }
            float psum = 0.f;
            #pragma unroll
            for (int uu = 0; uu < 5; ++uu) {
                float v = acc5[uu] * sa + cc;
                psum += (v > 0.f) ? v : (__expf(v) - 1.f);
            }
            smf[FPOOL + oo * 28 + j] = psum * 0.2f;
        }
    }

    __syncthreads();   // POOL complete

    // ---------- stage 3: token projection ----------
    if (u < 80) {
        int p = u >> 4, dd = u & 15;
        float acc = proj_b[dd];
        const float4* wp = reinterpret_cast<const float4*>(proj_w + dd * 80);
        #pragma unroll
        for (int i = 0; i < 20; ++i) {
            float4 w4 = wp[i];
            acc += w4.x * smf[FPOOL + ((4*i+0)/5) * 28 + p * 5 + ((4*i+0)%5)];
            acc += w4.y * smf[FPOOL + ((4*i+1)/5) * 28 + p * 5 + ((4*i+1)%5)];
            acc += w4.z * smf[FPOOL + ((4*i+2)/5) * 28 + p * 5 + ((4*i+2)%5)];
            acc += w4.w * smf[FPOOL + ((4*i+3)/5) * 28 + p * 5 + ((4*i+3)%5)];
        }
        smf[FTOK + p * 16 + dd] = acc;
    }

    __syncthreads();   // TOK complete

    // ---------- z init ----------
    const int d16 = u & 15;
    const int t6c = min(qg, 5);            // wave0: tokens 0-3; wave1: 4,5,5,5
    float z = ((t6c == 0) ? cls_token[d16] : smf[FTOK + (t6c - 1) * 16 + d16])
            + pe[t6c * 16 + d16];

    const int sb   = WEND + ss * SSTR;     // scratch base for this sample
    const int wav  = u >> 6;               // wave within the sample pair (0/1)
    const int al   = u & 63;

    // ---------- transformer: 6 layers ----------
    #pragma unroll 1
    for (int li = 0; li < 6; ++li) {
        __syncthreads();   // prev-layer weight/scratch reads done (and z-init)

        // --- stage layer weights into LDS (coalesced float4, all 256 threads) ---
        {
            const float4* s1 = reinterpret_cast<const float4*>(qkv_w + li * 3072);
            #pragma unroll
            for (int it = 0; it < 3; ++it) {
                int i = tid + it * 256;            // 768 float4
                float4 v = s1[i];
                int j = i >> 2, k = (i & 3) << 2;
                *reinterpret_cast<float4*>(&sm[WQKV + j * 20 + k]) = v;
            }
            {
                float4 v = reinterpret_cast<const float4*>(out_w + li * 1024)[tid];
                int j = tid >> 4, k = (tid & 15) << 2;
                *reinterpret_cast<float4*>(&sm[WOUT + j * 68 + k]) = v;
            }
            if (tid < 128) {
                float4 v = reinterpret_cast<const float4*>(mlp_w1 + li * 512)[tid];
                int j = tid >> 2, k = (tid & 3) << 2;
                *reinterpret_cast<float4*>(&sm[WM1 + j * 20 + k]) = v;
            } else {
                int i = tid - 128;
                float4 v = reinterpret_cast<const float4*>(mlp_w2 + li * 512)[i];
                int j = i >> 3, k = (i & 7) << 2;
                *reinterpret_cast<float4*>(&sm[WM2 + j * 36 + k]) = v;
            }
            if (tid < 192) sm[BQKV + tid] = qkv_b[li * 192 + tid];
            else if (tid < 208) sm[BOUT + tid - 192] = out_b[li * 16 + tid - 192];
            else if (tid < 240) sm[BM1 + tid - 208]  = mlp_b1[li * 32 + tid - 208];
            else               sm[BM2 + tid - 240]  = mlp_b2[li * 16 + tid - 240];
            if (tid >= 64 && tid < 80)        sm[LN1G + tid - 64]  = ln1_g[li * 16 + tid - 64];
            else if (tid >= 80 && tid < 96)   sm[LN1B + tid - 80]  = ln1_b[li * 16 + tid - 80];
            else if (tid >= 96 && tid < 112)  sm[LN2G + tid - 96]  = ln2_g[li * 16 + tid - 96];
            else if (tid >= 112 && tid < 128) sm[LN2B + tid - 112] = ln2_b[li * 16 + tid - 112];
        }
        __syncthreads();   // weights ready

        // --- LN1 -> H1 (wave-local rows) ---
        sm[sb + SH1 + t6c * 20 + d16] = ln_norm16(z, sm[LN1G + d16], sm[LN1B + d16]);
        WAVE_SYNC();

        float hr[16];
        {
            const float4* pA = reinterpret_cast<const float4*>(&sm[sb + SH1 + t6c * 20]);
            #pragma unroll
            for (int i = 0; i < 4; ++i) {
                float4 va = pA[i];
                hr[4*i+0] = va.x; hr[4*i+1] = va.y; hr[4*i+2] = va.z; hr[4*i+3] = va.w;
            }
        }

        // --- qkv: lane computes cols j = d16+16r for its token (weights from LDS) ---
        #pragma unroll 2
        for (int r = 0; r < 12; ++r) {
            int j = d16 + 16 * r;
            const float4* wp = reinterpret_cast<const float4*>(&sm[WQKV + j * 20]);
            float4 w0 = wp[0], w1_ = wp[1], w2_ = wp[2], w3_ = wp[3];
            sm[sb + SQKV + t6c * 196 + j] = sm[BQKV + j] + dot16(hr, w0, w1_, w2_, w3_);
        }
        __syncthreads();   // QKV ready (cross-wave: K,V of all tokens)

        // --- attention: wave0 -> queries 0-3 (32 lanes), wave1 -> 4,5 (16 lanes) ---
        {
            bool act = (wav == 0) ? (al < 32) : (al < 16);
            if (act) {
                int h  = al & 7;
                int qs = (wav == 0) ? (al >> 3) : 4 + (al >> 3);
                const int qoff = sb + SQKV + qs * 196 + h * 8;
                const float4* qp = reinterpret_cast<const float4*>(&sm[qoff]);
                float4 q0 = qp[0], q1 = qp[1];
                float sc[6];
                #pragma unroll
                for (int t = 0; t < 6; ++t) {
                    const float4* kp = reinterpret_cast<const float4*>(&sm[sb + SQKV + t * 196 + 64 + h * 8]);
                    float4 k0 = kp[0], k1 = kp[1];
                    sc[t] = (q0.x*k0.x + q0.y*k0.y + q0.z*k0.z + q0.w*k0.w
                           + q1.x*k1.x + q1.y*k1.y + q1.z*k1.z + q1.w*k1.w)
                           * 0.35355339059327373f;
                }
                float mx = sc[0];
                #pragma unroll
                for (int t = 1; t < 6; ++t) mx = fmaxf(mx, sc[t]);
                float ssum = 0.f;
                #pragma unroll
                for (int t = 0; t < 6; ++t) { sc[t] = __expf(sc[t] - mx); ssum += sc[t]; }
                float inv = 1.f / ssum;
                float o0=0.f,o1=0.f,o2=0.f,o3=0.f,o4=0.f,o5=0.f,o6=0.f,o7=0.f;
                #pragma unroll
                for (int t = 0; t < 6; ++t) {
                    const float4* vp = reinterpret_cast<const float4*>(&sm[sb + SQKV + t * 196 + 128 + h * 8]);
                    float4 v0 = vp[0], v1 = vp[1];
                    float a = sc[t] * inv;
                    o0 += a*v0.x; o1 += a*v0.y; o2 += a*v0.z; o3 += a*v0.w;
                    o4 += a*v1.x; o5 += a*v1.y; o6 += a*v1.z; o7 += a*v1.w;
                }
                // overwrite own q slot with O (only this lane ever read it)
                *reinterpret_cast<float4*>(&sm[qoff    ]) = float4{o0,o1,o2,o3};
                *reinterpret_cast<float4*>(&sm[qoff + 4]) = float4{o4,o5,o6,o7};
            }
        }
        WAVE_SYNC();   // O rows are wave-local (own wave computed own tokens)

        // --- out projection + residual ---
        {
            const float4* wop = reinterpret_cast<const float4*>(&sm[WOUT + d16 * 68]);
            const float4* oa  = reinterpret_cast<const float4*>(&sm[sb + SQKV + t6c * 196]);
            float acc = sm[BOUT + d16];
            #pragma unroll 4
            for (int i = 0; i < 16; ++i) {
                float4 w = wop[i];
                float4 va = oa[i];
                acc += va.x*w.x + va.y*w.y + va.z*w.z + va.w*w.w;
            }
            z += acc;
        }

        // --- LN2 -> H1 (wave-local) ---
        sm[sb + SH1 + t6c * 20 + d16] = ln_norm16(z, sm[LN2G + d16], sm[LN2B + d16]);
        WAVE_SYNC();
        {
            const float4* pA = reinterpret_cast<const float4*>(&sm[sb + SH1 + t6c * 20]);
            #pragma unroll
            for (int i = 0; i < 4; ++i) {
                float4 va = pA[i];
                hr[4*i+0] = va.x; hr[4*i+1] = va.y; hr[4*i+2] = va.z; hr[4*i+3] = va.w;
            }
        }

        // --- mlp1 + GELU -> MHS (wave-local) ---
        #pragma unroll
        for (int r = 0; r < 2; ++r) {
            int uu = d16 + 16 * r;
            const float4* wp = reinterpret_cast<const float4*>(&sm[WM1 + uu * 20]);
            float4 w0 = wp[0], w1_ = wp[1], w2_ = wp[2], w3_ = wp[3];
            float a = sm[BM1 + uu] + dot16(hr, w0, w1_, w2_, w3_);
            sm[sb + SMHS + t6c * 36 + uu] = gelu_exact(a);
        }
        WAVE_SYNC();

        // --- mlp2 + residual (wave-local MHS read) ---
        {
            const float4* wp = reinterpret_cast<const float4*>(&sm[WM2 + d16 * 36]);
            const float4* mA = reinterpret_cast<const float4*>(&sm[sb + SMHS + t6c * 36]);
            float acc = sm[BM2 + d16];
            #pragma unroll
            for (int i = 0; i < 8; ++i) {
                float4 w = wp[i];
                float4 va = mA[i];
                acc += va.x*w.x + va.y*w.y + va.z*w.z + va.w*w.w;
            }
            z += acc;
        }
        // loop-top __syncthreads orders all cross-wave reads before restaging
    }

    // ---------- head: LN(cls) -> 2-way linear -> softmax ----------
    if (u < 16) {
        float cv = ln_norm16(z, head_ln_g[d16], head_ln_b[d16]);
        float p0 = cv * head_w[d16];
        float p1 = cv * head_w[16 + d16];
        #pragma unroll
        for (int off = 8; off >= 1; off >>= 1) {
            p0 += __shfl_xor(p0, off, 16);
            p1 += __shfl_xor(p1, off, 16);
        }
        if (u == 0) {
            float l0 = p0 + head_b[0], l1 = p1 + head_b[1];
            float mx = fmaxf(l0, l1);
            float e0 = __expf(l0 - mx), e1 = __expf(l1 - mx);
            float inv = 1.f / (e0 + e1);
            out[b2 * 2 + 0] = e0 * inv;
            out[b2 * 2 + 1] = e1 * inv;
        }
    }
}

extern "C" void kernel_launch(void* const* d_in, const int* in_sizes, int n_in,
                              void* d_out, int out_size, void* d_ws, size_t ws_size,
                              hipStream_t stream) {
    (void)n_in; (void)d_ws; (void)ws_size; (void)out_size;
    const float* a0  = (const float*)d_in[0];
    const float* a1  = (const float*)d_in[1];
    const float* a2  = (const float*)d_in[2];
    const float* a3  = (const float*)d_in[3];
    const float* a4  = (const float*)d_in[4];
    const float* a5  = (const float*)d_in[5];
    const float* a6  = (const float*)d_in[6];
    const float* a7  = (const float*)d_in[7];
    const float* a8  = (const float*)d_in[8];
    const float* a9  = (const float*)d_in[9];
    const float* a10 = (const float*)d_in[10];
    const float* a11 = (const float*)d_in[11];
    const float* a12 = (const float*)d_in[12];
    const float* a13 = (const float*)d_in[13];
    const float* a14 = (const float*)d_in[14];
    const float* a15 = (const float*)d_in[15];
    const float* a16 = (const float*)d_in[16];
    const float* a17 = (const float*)d_in[17];
    const float* a18 = (const float*)d_in[18];
    const float* a19 = (const float*)d_in[19];
    const float* a20 = (const float*)d_in[20];
    const float* a21 = (const float*)d_in[21];
    const float* a22 = (const float*)d_in[22];
    const float* a23 = (const float*)d_in[23];
    const float* a24 = (const float*)d_in[24];
    const float* a25 = (const float*)d_in[25];
    const float* a26 = (const float*)d_in[26];
    const float* a27 = (const float*)d_in[27];
    const float* a28 = (const float*)d_in[28];
    const float* a29 = (const float*)d_in[29];
    const float* a30 = (const float*)d_in[30];
    const float* a31 = (const float*)d_in[31];
    const float* a32 = (const float*)d_in[32];

    int Bn = in_sizes[0] / (64 * 125);          // 2048 samples, 2 per block
    eegnet_vit_fused<<<Bn / 2, TB, 0, stream>>>(
        a0, a1, a2, a3, a4, a5, a6, a7, a8, a9, a10, a11, a12, a13, a14, a15, a16,
        a17, a18, a19, a20, a21, a22, a23, a24, a25, a26, a27, a28, a29, a30, a31, a32,
        (float*)d_out);
}

// Round 7
// 242.850 us; speedup vs baseline: 1.3488x; 1.0229x over previous
//
#include <hip/hip_runtime.h>

// Wave-synchronous fence: DS ops complete in order within a wave (ISA
// guarantee); this only stops the COMPILER from reordering/caching LDS.
#define WAVE_SYNC() do { asm volatile("" ::: "memory"); \
                         __builtin_amdgcn_wave_barrier(); \
                         asm volatile("" ::: "memory"); } while (0)

__device__ __forceinline__ float ln_norm16(float z, float g, float bb) {
    float s = z, q = z * z;
    #pragma unroll
    for (int off = 8; off >= 1; off >>= 1) {
        s += __shfl_xor(s, off, 16);
        q += __shfl_xor(q, off, 16);
    }
    float mean = s * 0.0625f;
    float var  = q * 0.0625f - mean * mean;
    return (z - mean) * rsqrtf(var + 1e-5f) * g + bb;
}

__device__ __forceinline__ float gelu_exact(float a) {
    float xa = fabsf(a) * 0.70710678118654752f;
    float tt = 1.f / (1.f + 0.3275911f * xa);
    float poly = tt * (0.254829592f + tt * (-0.284496736f + tt * (1.421413741f
               + tt * (-1.453152027f + tt * 1.061405429f))));
    float erfv = 1.f - poly * __expf(-xa * xa);
    erfv = a >= 0.f ? erfv : -erfv;
    return 0.5f * a * (1.f + erfv);
}

__device__ __forceinline__ float dot16(const float* h, float4 w0, float4 w1,
                                       float4 w2, float4 w3) {
    return h[0]*w0.x + h[1]*w0.y + h[2]*w0.z + h[3]*w0.w
         + h[4]*w1.x + h[5]*w1.y + h[6]*w1.z + h[7]*w1.w
         + h[8]*w2.x + h[9]*w2.y + h[10]*w2.z + h[11]*w2.w
         + h[12]*w3.x + h[13]*w3.y + h[14]*w3.z + h[15]*w3.w;
}

// ========================= Kernel F: conv frontend ===========================
// 1 sample per 128-thread block; writes TOK (80 f32/sample) to workspace.
#define FXSP  0       // 16 x 196 zero-padded
#define FPOOL 3136    // 16 x 28
#define F_TOT 3584    // 14.3 KB -> grid-limited 8 blocks/CU = 16 waves/CU

extern "C" __global__ __launch_bounds__(128, 2)
void eegnet_frontend(
    const float* __restrict__ x,
    const float* __restrict__ conv_t_w, const float* __restrict__ conv_t_b,
    const float* __restrict__ bn1_g, const float* __restrict__ bn1_b,
    const float* __restrict__ bn1_m, const float* __restrict__ bn1_v,
    const float* __restrict__ conv_s_w, const float* __restrict__ conv_s_b,
    const float* __restrict__ bn2_g, const float* __restrict__ bn2_b,
    const float* __restrict__ bn2_m, const float* __restrict__ bn2_v,
    const float* __restrict__ proj_w, const float* __restrict__ proj_b,
    float* __restrict__ tokws)
{
    __shared__ __align__(16) float sm[F_TOT];
    const int b   = blockIdx.x;
    const int tid = threadIdx.x;

    // zero ONLY the pad zones of XSP: per row [0,32) and [157,196)
    for (int i = tid; i < 16 * 71; i += 128) {
        int row = i / 71, k = i - row * 71;
        int off = (k < 32) ? k : (k + 125);
        sm[FXSP + row * 196 + off] = 0.f;
    }

    // stage 1: spatial conv, one t-column per lane
    {
        const float* xb = x + (size_t)b * 8000;
        const int t = min(tid, 124);
        float a0[16];
        #pragma unroll
        for (int o = 0; o < 16; ++o) a0[o] = 0.f;
        #pragma unroll 8
        for (int c = 0; c < 64; ++c) {
            float xv = xb[c * 125 + t];
            #pragma unroll
            for (int o = 0; o < 16; ++o)
                a0[o] += conv_s_w[o * 64 + c] * xv;    // wave-uniform -> s_load
        }
        if (tid < 125) {
            #pragma unroll
            for (int o = 0; o < 16; ++o)
                sm[FXSP + o * 196 + 32 + t] = a0[o];
        }
    }

    // fused BN constants + temporal taps (per-lane, oo = tid&15)
    const int oo = tid & 15, qg = tid >> 4, gg = oo >> 1;
    float sa, cc;
    {
        float s1 = bn1_g[gg] * rsqrtf(bn1_v[gg] + 1e-5f);
        float b1 = (conv_t_b[gg] - bn1_m[gg]) * s1 + bn1_b[gg];
        float s2 = bn2_g[oo] * rsqrtf(bn2_v[oo] + 1e-5f);
        float ssum = 0.f;
        const float4* csw = reinterpret_cast<const float4*>(conv_s_w + oo * 64);
        #pragma unroll
        for (int i = 0; i < 16; ++i) {
            float4 v = csw[i];
            ssum += v.x + v.y + v.z + v.w;
        }
        sa = s1 * s2;
        cc = (b1 * ssum + conv_s_b[oo] - bn2_m[oo]) * s2 + bn2_b[oo];
    }
    float wt[63];
    #pragma unroll
    for (int k = 0; k < 63; ++k) wt[k] = conv_t_w[gg * 63 + k];

    __syncthreads();   // XSP complete

    // stage 2: temporal conv + BN + ELU + avg-pool
    #pragma unroll 1
    for (int jj = 0; jj < 4; ++jj) {
        int j = qg + 8 * jj;
        if (j < 25) {
            int base = FXSP + oo * 196 + 5 * j + 1;
            float acc5[5] = {0.f, 0.f, 0.f, 0.f, 0.f};
            #pragma unroll
            for (int m = 0; m < 67; ++m) {
                float xv = sm[base + m];
                #pragma unroll
                for (int uu = 0; uu < 5; ++uu)
                    if (uu <= m && m - uu <= 62) acc5[uu] += wt[m - uu] * xv;
            }
            float psum = 0.f;
            #pragma unroll
            for (int uu = 0; uu < 5; ++uu) {
                float v = acc5[uu] * sa + cc;
                psum += (v > 0.f) ? v : (__expf(v) - 1.f);
            }
            sm[FPOOL + oo * 28 + j] = psum * 0.2f;
        }
    }

    __syncthreads();   // POOL complete

    // stage 3: token projection, one output per lane -> global TOK
    if (tid < 80) {
        int p = tid >> 4, dd = tid & 15;
        float acc = proj_b[dd];
        const float4* wp = reinterpret_cast<const float4*>(proj_w + dd * 80);
        #pragma unroll
        for (int i = 0; i < 20; ++i) {
            float4 w4 = wp[i];
            acc += w4.x * sm[FPOOL + ((4*i+0)/5) * 28 + p * 5 + ((4*i+0)%5)];
            acc += w4.y * sm[FPOOL + ((4*i+1)/5) * 28 + p * 5 + ((4*i+1)%5)];
            acc += w4.z * sm[FPOOL + ((4*i+2)/5) * 28 + p * 5 + ((4*i+2)%5)];
            acc += w4.w * sm[FPOOL + ((4*i+3)/5) * 28 + p * 5 + ((4*i+3)%5)];
        }
        tokws[b * 80 + tid] = acc;   // tid == p*16+dd
    }
}

// ===================== Kernel T: transformer + head ==========================
// 256 threads = 2 units x 128; each unit processes 2 samples (dual-sample ILP:
// every LDS weight-row read feeds two independent FMA chains).
#define WQKV 0        // 192 rows x 20 (16 used)
#define BQKV 3840     // 192
#define WOUT 4032     // 16 rows x 68 (64 used)
#define BOUT 5120     // 16
#define WM1  5136     // 32 rows x 20
#define BM1  5776     // 32
#define WM2  5808     // 16 rows x 36 (32 used)
#define BM2  6384     // 16
#define LN1G 6400
#define LN1B 6416
#define LN2G 6432
#define LN2B 6448
#define WEND 6464
#define SSTR 1568     // per-sample scratch stride
#define SH1  0        // 6 x 20
#define SQKV 128      // 6 x 196 (q at +0 -> O after attention, k +64, v +128)
#define SMHS 1312     // 6 x 36
#define T_TOT (WEND + 4*SSTR)   // 12736 floats = 50.9 KB -> 2-3 blocks/CU

extern "C" __global__ __launch_bounds__(256, 2)
void eegnet_transformer(
    const float* __restrict__ cls_token, const float* __restrict__ pe,
    const float* __restrict__ qkv_w, const float* __restrict__ qkv_b,
    const float* __restrict__ out_w, const float* __restrict__ out_b,
    const float* __restrict__ ln1_g, const float* __restrict__ ln1_b,
    const float* __restrict__ ln2_g, const float* __restrict__ ln2_b,
    const float* __restrict__ mlp_w1, const float* __restrict__ mlp_b1,
    const float* __restrict__ mlp_w2, const float* __restrict__ mlp_b2,
    const float* __restrict__ head_ln_g, const float* __restrict__ head_ln_b,
    const float* __restrict__ head_w, const float* __restrict__ head_b,
    const float* __restrict__ tokws, float* __restrict__ out)
{
    __shared__ __align__(16) float sm[T_TOT];
    const int tid = threadIdx.x;
    const int ss  = tid >> 7;              // unit (0/1)
    const int u   = tid & 127;
    const int sA  = blockIdx.x * 4 + ss * 2;   // two samples: sA, sA+1
    const int d16 = u & 15, qg = u >> 4;
    const int t6c = min(qg, 5);            // wave0: tokens 0-3; wave1: 4,5,5,5
    const int wav = u >> 6, al = u & 63;
    const int sbA = WEND + (ss * 2    ) * SSTR;
    const int sbB = WEND + (ss * 2 + 1) * SSTR;

    // z init (TOK from workspace; cls+pe from global)
    float zA, zB;
    {
        float peV = pe[t6c * 16 + d16];
        if (t6c == 0) {
            float cv = cls_token[d16];
            zA = cv + peV; zB = cv + peV;
        } else {
            zA = tokws[(sA    ) * 80 + (t6c - 1) * 16 + d16] + peV;
            zB = tokws[(sA + 1) * 80 + (t6c - 1) * 16 + d16] + peV;
        }
    }

    #pragma unroll 1
    for (int li = 0; li < 6; ++li) {
        __syncthreads();   // prev-layer reads done before restaging

        // --- stage layer weights into LDS (coalesced float4, 256 threads) ---
        {
            const float4* s1 = reinterpret_cast<const float4*>(qkv_w + li * 3072);
            #pragma unroll
            for (int it = 0; it < 3; ++it) {
                int i = tid + it * 256;
                float4 v = s1[i];
                int j = i >> 2, k = (i & 3) << 2;
                *reinterpret_cast<float4*>(&sm[WQKV + j * 20 + k]) = v;
            }
            {
                float4 v = reinterpret_cast<const float4*>(out_w + li * 1024)[tid];
                int j = tid >> 4, k = (tid & 15) << 2;
                *reinterpret_cast<float4*>(&sm[WOUT + j * 68 + k]) = v;
            }
            if (tid < 128) {
                float4 v = reinterpret_cast<const float4*>(mlp_w1 + li * 512)[tid];
                int j = tid >> 2, k = (tid & 3) << 2;
                *reinterpret_cast<float4*>(&sm[WM1 + j * 20 + k]) = v;
            } else {
                int i = tid - 128;
                float4 v = reinterpret_cast<const float4*>(mlp_w2 + li * 512)[i];
                int j = i >> 3, k = (i & 7) << 2;
                *reinterpret_cast<float4*>(&sm[WM2 + j * 36 + k]) = v;
            }
            if (tid < 192) sm[BQKV + tid] = qkv_b[li * 192 + tid];
            else if (tid < 208) sm[BOUT + tid - 192] = out_b[li * 16 + tid - 192];
            else if (tid < 240) sm[BM1 + tid - 208]  = mlp_b1[li * 32 + tid - 208];
            else               sm[BM2 + tid - 240]  = mlp_b2[li * 16 + tid - 240];
            if (tid >= 64 && tid < 80)        sm[LN1G + tid - 64]  = ln1_g[li * 16 + tid - 64];
            else if (tid >= 80 && tid < 96)   sm[LN1B + tid - 80]  = ln1_b[li * 16 + tid - 80];
            else if (tid >= 96 && tid < 112)  sm[LN2G + tid - 96]  = ln2_g[li * 16 + tid - 96];
            else if (tid >= 112 && tid < 128) sm[LN2B + tid - 112] = ln2_b[li * 16 + tid - 112];
        }
        __syncthreads();   // weights ready

        // --- LN1 -> H1 (both samples) ---
        {
            float g = sm[LN1G + d16], bb = sm[LN1B + d16];
            sm[sbA + SH1 + t6c * 20 + d16] = ln_norm16(zA, g, bb);
            sm[sbB + SH1 + t6c * 20 + d16] = ln_norm16(zB, g, bb);
        }
        WAVE_SYNC();

        float hrA[16], hrB[16];
        {
            const float4* pA = reinterpret_cast<const float4*>(&sm[sbA + SH1 + t6c * 20]);
            const float4* pB = reinterpret_cast<const float4*>(&sm[sbB + SH1 + t6c * 20]);
            #pragma unroll
            for (int i = 0; i < 4; ++i) {
                float4 va = pA[i], vb = pB[i];
                hrA[4*i+0]=va.x; hrA[4*i+1]=va.y; hrA[4*i+2]=va.z; hrA[4*i+3]=va.w;
                hrB[4*i+0]=vb.x; hrB[4*i+1]=vb.y; hrB[4*i+2]=vb.z; hrB[4*i+3]=vb.w;
            }
        }

        // --- qkv: weight row read once, two dot products ---
        #pragma unroll 2
        for (int r = 0; r < 12; ++r) {
            int j = d16 + 16 * r;
            const float4* wp = reinterpret_cast<const float4*>(&sm[WQKV + j * 20]);
            float4 w0 = wp[0], w1_ = wp[1], w2_ = wp[2], w3_ = wp[3];
            float bb = sm[BQKV + j];
            sm[sbA + SQKV + t6c * 196 + j] = bb + dot16(hrA, w0, w1_, w2_, w3_);
            sm[sbB + SQKV + t6c * 196 + j] = bb + dot16(hrB, w0, w1_, w2_, w3_);
        }
        __syncthreads();   // QKV ready (cross-wave K,V)

        // --- attention: wave0 -> queries 0-3 (32 lanes), wave1 -> 4,5 (16) ---
        {
            bool act = (wav == 0) ? (al < 32) : (al < 16);
            if (act) {
                int h  = al & 7;
                int qs = (wav == 0) ? (al >> 3) : 4 + (al >> 3);
                const int qoffA = sbA + SQKV + qs * 196 + h * 8;
                const int qoffB = sbB + SQKV + qs * 196 + h * 8;
                const float4* qpA = reinterpret_cast<const float4*>(&sm[qoffA]);
                const float4* qpB = reinterpret_cast<const float4*>(&sm[qoffB]);
                float4 qA0 = qpA[0], qA1 = qpA[1], qB0 = qpB[0], qB1 = qpB[1];
                float scA[6], scB[6];
                #pragma unroll
                for (int t = 0; t < 6; ++t) {
                    const float4* kA = reinterpret_cast<const float4*>(&sm[sbA + SQKV + t * 196 + 64 + h * 8]);
                    const float4* kB = reinterpret_cast<const float4*>(&sm[sbB + SQKV + t * 196 + 64 + h * 8]);
                    float4 a0 = kA[0], a1 = kA[1], b0 = kB[0], b1 = kB[1];
                    scA[t] = (qA0.x*a0.x + qA0.y*a0.y + qA0.z*a0.z + qA0.w*a0.w
                            + qA1.x*a1.x + qA1.y*a1.y + qA1.z*a1.z + qA1.w*a1.w)
                            * 0.35355339059327373f;
                    scB[t] = (qB0.x*b0.x + qB0.y*b0.y + qB0.z*b0.z + qB0.w*b0.w
                            + qB1.x*b1.x + qB1.y*b1.y + qB1.z*b1.z + qB1.w*b1.w)
                            * 0.35355339059327373f;
                }
                float mxA = scA[0], mxB = scB[0];
                #pragma unroll
                for (int t = 1; t < 6; ++t) { mxA = fmaxf(mxA, scA[t]); mxB = fmaxf(mxB, scB[t]); }
                float suA = 0.f, suB = 0.f;
                #pragma unroll
                for (int t = 0; t < 6; ++t) {
                    scA[t] = __expf(scA[t] - mxA); suA += scA[t];
                    scB[t] = __expf(scB[t] - mxB); suB += scB[t];
                }
                float ivA = 1.f / suA, ivB = 1.f / suB;
                float oA[8] = {0,0,0,0,0,0,0,0}, oB[8] = {0,0,0,0,0,0,0,0};
                #pragma unroll
                for (int t = 0; t < 6; ++t) {
                    const float4* vA = reinterpret_cast<const float4*>(&sm[sbA + SQKV + t * 196 + 128 + h * 8]);
                    const float4* vB = reinterpret_cast<const float4*>(&sm[sbB + SQKV + t * 196 + 128 + h * 8]);
                    float4 a0 = vA[0], a1 = vA[1], b0 = vB[0], b1 = vB[1];
                    float aa = scA[t] * ivA, ab = scB[t] * ivB;
                    oA[0]+=aa*a0.x; oA[1]+=aa*a0.y; oA[2]+=aa*a0.z; oA[3]+=aa*a0.w;
                    oA[4]+=aa*a1.x; oA[5]+=aa*a1.y; oA[6]+=aa*a1.z; oA[7]+=aa*a1.w;
                    oB[0]+=ab*b0.x; oB[1]+=ab*b0.y; oB[2]+=ab*b0.z; oB[3]+=ab*b0.w;
                    oB[4]+=ab*b1.x; oB[5]+=ab*b1.y; oB[6]+=ab*b1.z; oB[7]+=ab*b1.w;
                }
                *reinterpret_cast<float4*>(&sm[qoffA    ]) = float4{oA[0],oA[1],oA[2],oA[3]};
                *reinterpret_cast<float4*>(&sm[qoffA + 4]) = float4{oA[4],oA[5],oA[6],oA[7]};
                *reinterpret_cast<float4*>(&sm[qoffB    ]) = float4{oB[0],oB[1],oB[2],oB[3]};
                *reinterpret_cast<float4*>(&sm[qoffB + 4]) = float4{oB[4],oB[5],oB[6],oB[7]};
            }
        }
        WAVE_SYNC();   // O rows are wave-local (own wave computed own tokens)

        // --- out projection + residual (weight row once, two dots) ---
        {
            const float4* wop = reinterpret_cast<const float4*>(&sm[WOUT + d16 * 68]);
            const float4* oaA = reinterpret_cast<const float4*>(&sm[sbA + SQKV + t6c * 196]);
            const float4* oaB = reinterpret_cast<const float4*>(&sm[sbB + SQKV + t6c * 196]);
            float bb = sm[BOUT + d16];
            float aA = bb, aB = bb;
            #pragma unroll 4
            for (int i = 0; i < 16; ++i) {
                float4 w = wop[i];
                float4 va = oaA[i], vb = oaB[i];
                aA += va.x*w.x + va.y*w.y + va.z*w.z + va.w*w.w;
                aB += vb.x*w.x + vb.y*w.y + vb.z*w.z + vb.w*w.w;
            }
            zA += aA; zB += aB;
        }

        // --- LN2 -> H1 (both samples) ---
        {
            float g = sm[LN2G + d16], bb = sm[LN2B + d16];
            sm[sbA + SH1 + t6c * 20 + d16] = ln_norm16(zA, g, bb);
            sm[sbB + SH1 + t6c * 20 + d16] = ln_norm16(zB, g, bb);
        }
        WAVE_SYNC();
        {
            const float4* pA = reinterpret_cast<const float4*>(&sm[sbA + SH1 + t6c * 20]);
            const float4* pB = reinterpret_cast<const float4*>(&sm[sbB + SH1 + t6c * 20]);
            #pragma unroll
            for (int i = 0; i < 4; ++i) {
                float4 va = pA[i], vb = pB[i];
                hrA[4*i+0]=va.x; hrA[4*i+1]=va.y; hrA[4*i+2]=va.z; hrA[4*i+3]=va.w;
                hrB[4*i+0]=vb.x; hrB[4*i+1]=vb.y; hrB[4*i+2]=vb.z; hrB[4*i+3]=vb.w;
            }
        }

        // --- mlp1 + GELU -> MHS ---
        #pragma unroll
        for (int r = 0; r < 2; ++r) {
            int uu = d16 + 16 * r;
            const float4* wp = reinterpret_cast<const float4*>(&sm[WM1 + uu * 20]);
            float4 w0 = wp[0], w1_ = wp[1], w2_ = wp[2], w3_ = wp[3];
            float bb = sm[BM1 + uu];
            float aA = bb + dot16(hrA, w0, w1_, w2_, w3_);
            float aB = bb + dot16(hrB, w0, w1_, w2_, w3_);
            sm[sbA + SMHS + t6c * 36 + uu] = gelu_exact(aA);
            sm[sbB + SMHS + t6c * 36 + uu] = gelu_exact(aB);
        }
        WAVE_SYNC();

        // --- mlp2 + residual ---
        {
            const float4* wp = reinterpret_cast<const float4*>(&sm[WM2 + d16 * 36]);
            const float4* mA = reinterpret_cast<const float4*>(&sm[sbA + SMHS + t6c * 36]);
            const float4* mB = reinterpret_cast<const float4*>(&sm[sbB + SMHS + t6c * 36]);
            float bb = sm[BM2 + d16];
            float aA = bb, aB = bb;
            #pragma unroll
            for (int i = 0; i < 8; ++i) {
                float4 w = wp[i];
                float4 va = mA[i], vb = mB[i];
                aA += va.x*w.x + va.y*w.y + va.z*w.z + va.w*w.w;
                aB += vb.x*w.x + vb.y*w.y + vb.z*w.z + vb.w*w.w;
            }
            zA += aA; zB += aB;
        }
        // loop-top __syncthreads orders cross-wave reads before restaging
    }

    // ---------- head: LN(cls) -> 2-way linear -> softmax, both samples ----------
    if (u < 16) {
        float g = head_ln_g[d16], bb = head_ln_b[d16];
        float w0 = head_w[d16], w1 = head_w[16 + d16];
        float cvA = ln_norm16(zA, g, bb);
        float cvB = ln_norm16(zB, g, bb);
        float pA0 = cvA * w0, pA1 = cvA * w1;
        float pB0 = cvB * w0, pB1 = cvB * w1;
        #pragma unroll
        for (int off = 8; off >= 1; off >>= 1) {
            pA0 += __shfl_xor(pA0, off, 16);
            pA1 += __shfl_xor(pA1, off, 16);
            pB0 += __shfl_xor(pB0, off, 16);
            pB1 += __shfl_xor(pB1, off, 16);
        }
        if (u == 0) {
            float hb0 = head_b[0], hb1 = head_b[1];
            {
                float l0 = pA0 + hb0, l1 = pA1 + hb1;
                float mx = fmaxf(l0, l1);
                float e0 = __expf(l0 - mx), e1 = __expf(l1 - mx);
                float inv = 1.f / (e0 + e1);
                out[sA * 2 + 0] = e0 * inv;
                out[sA * 2 + 1] = e1 * inv;
            }
            {
                float l0 = pB0 + hb0, l1 = pB1 + hb1;
                float mx = fmaxf(l0, l1);
                float e0 = __expf(l0 - mx), e1 = __expf(l1 - mx);
                float inv = 1.f / (e0 + e1);
                out[(sA + 1) * 2 + 0] = e0 * inv;
                out[(sA + 1) * 2 + 1] = e1 * inv;
            }
        }
    }
}

extern "C" void kernel_launch(void* const* d_in, const int* in_sizes, int n_in,
                              void* d_out, int out_size, void* d_ws, size_t ws_size,
                              hipStream_t stream) {
    (void)n_in; (void)ws_size; (void)out_size;
    const float* a0  = (const float*)d_in[0];   // x
    const float* a1  = (const float*)d_in[1];   // conv_t_w
    const float* a2  = (const float*)d_in[2];   // conv_t_b
    const float* a3  = (const float*)d_in[3];   // bn1_g
    const float* a4  = (const float*)d_in[4];   // bn1_b
    const float* a5  = (const float*)d_in[5];   // bn1_m
    const float* a6  = (const float*)d_in[6];   // bn1_v
    const float* a7  = (const float*)d_in[7];   // conv_s_w
    const float* a8  = (const float*)d_in[8];   // conv_s_b
    const float* a9  = (const float*)d_in[9];   // bn2_g
    const float* a10 = (const float*)d_in[10];  // bn2_b
    const float* a11 = (const float*)d_in[11];  // bn2_m
    const float* a12 = (const float*)d_in[12];  // bn2_v
    const float* a13 = (const float*)d_in[13];  // proj_w
    const float* a14 = (const float*)d_in[14];  // proj_b
    const float* a15 = (const float*)d_in[15];  // cls_token
    const float* a16 = (const float*)d_in[16];  // pe
    const float* a17 = (const float*)d_in[17];  // qkv_w
    const float* a18 = (const float*)d_in[18];  // qkv_b
    const float* a19 = (const float*)d_in[19];  // out_w
    const float* a20 = (const float*)d_in[20];  // out_b
    const float* a21 = (const float*)d_in[21];  // ln1_g
    const float* a22 = (const float*)d_in[22];  // ln1_b
    const float* a23 = (const float*)d_in[23];  // ln2_g
    const float* a24 = (const float*)d_in[24];  // ln2_b
    const float* a25 = (const float*)d_in[25];  // mlp_w1
    const float* a26 = (const float*)d_in[26];  // mlp_b1
    const float* a27 = (const float*)d_in[27];  // mlp_w2
    const float* a28 = (const float*)d_in[28];  // mlp_b2
    const float* a29 = (const float*)d_in[29];  // head_ln_g
    const float* a30 = (const float*)d_in[30];  // head_ln_b
    const float* a31 = (const float*)d_in[31];  // head_w
    const float* a32 = (const float*)d_in[32];  // head_b

    int Bn = in_sizes[0] / (64 * 125);          // 2048
    float* tokws = (float*)d_ws;                // 2048 x 80 f32 = 640 KB

    eegnet_frontend<<<Bn, 128, 0, stream>>>(
        a0, a1, a2, a3, a4, a5, a6, a7, a8, a9, a10, a11, a12, a13, a14, tokws);

    eegnet_transformer<<<Bn / 4, 256, 0, stream>>>(
        a15, a16, a17, a18, a19, a20, a21, a22, a23, a24, a25, a26, a27, a28,
        a29, a30, a31, a32, tokws, (float*)d_out);
}

// Round 8
// 232.954 us; speedup vs baseline: 1.4061x; 1.0425x over previous
//
#include <hip/hip_runtime.h>

// Wave-synchronous fence: DS ops complete in order within a wave (ISA
// guarantee); this only stops the COMPILER from reordering/caching LDS.
#define WAVE_SYNC() do { asm volatile("" ::: "memory"); \
                         __builtin_amdgcn_wave_barrier(); \
                         asm volatile("" ::: "memory"); } while (0)

__device__ __forceinline__ float ln_norm16(float z, float g, float bb) {
    float s = z, q = z * z;
    #pragma unroll
    for (int off = 8; off >= 1; off >>= 1) {
        s += __shfl_xor(s, off, 16);
        q += __shfl_xor(q, off, 16);
    }
    float mean = s * 0.0625f;
    float var  = q * 0.0625f - mean * mean;
    return (z - mean) * rsqrtf(var + 1e-5f) * g + bb;
}

__device__ __forceinline__ float gelu_exact(float a) {
    float xa = fabsf(a) * 0.70710678118654752f;
    float tt = 1.f / (1.f + 0.3275911f * xa);
    float poly = tt * (0.254829592f + tt * (-0.284496736f + tt * (1.421413741f
               + tt * (-1.453152027f + tt * 1.061405429f))));
    float erfv = 1.f - poly * __expf(-xa * xa);
    erfv = a >= 0.f ? erfv : -erfv;
    return 0.5f * a * (1.f + erfv);
}

__device__ __forceinline__ float dot16(const float* h, float4 w0, float4 w1,
                                       float4 w2, float4 w3) {
    return h[0]*w0.x + h[1]*w0.y + h[2]*w0.z + h[3]*w0.w
         + h[4]*w1.x + h[5]*w1.y + h[6]*w1.z + h[7]*w1.w
         + h[8]*w2.x + h[9]*w2.y + h[10]*w2.z + h[11]*w2.w
         + h[12]*w3.x + h[13]*w3.y + h[14]*w3.z + h[15]*w3.w;
}

// ========================= Kernel F: conv frontend ===========================
// 1 sample per 64-lane WAVE; zero __syncthreads (wave-local fences only).
// All waves fully independent -> any resident wave can always issue.
#define F_XS  0       // 16 x 198 zero-padded (stride 198: stage-2 banks <=2-way)
#define F_PL  3168    // 16 x 28
#define F_TOT 3616    // 14.5 KB -> 11 blocks/CU LDS limit (8 needed)

extern "C" __global__ __launch_bounds__(64, 2)
void eegnet_frontend(
    const float* __restrict__ x,
    const float* __restrict__ conv_t_w, const float* __restrict__ conv_t_b,
    const float* __restrict__ bn1_g, const float* __restrict__ bn1_b,
    const float* __restrict__ bn1_m, const float* __restrict__ bn1_v,
    const float* __restrict__ conv_s_w, const float* __restrict__ conv_s_b,
    const float* __restrict__ bn2_g, const float* __restrict__ bn2_b,
    const float* __restrict__ bn2_m, const float* __restrict__ bn2_v,
    const float* __restrict__ proj_w, const float* __restrict__ proj_b,
    float* __restrict__ tokws)
{
    __shared__ __align__(16) float sm[F_TOT];
    const int b    = blockIdx.x;
    const int lane = threadIdx.x;

    // zero ONLY the pad zones: per row [0,32) and [157,198) -> 73 per row
    for (int i = lane; i < 16 * 73; i += 64) {
        int row = i / 73, k = i - row * 73;
        int off = (k < 32) ? k : (k + 125);
        sm[F_XS + row * 198 + off] = 0.f;
    }

    // ---- stage 1: spatial conv; lane covers t=lane and t=64+lane ----
    // unroll 16 -> 32 outstanding global loads to cover L3 latency.
    {
        const float* xb = x + (size_t)b * 8000;
        const int l2 = min(lane, 60);                // clamp OOB tail col
        float a0[16], a1[16];
        #pragma unroll
        for (int o = 0; o < 16; ++o) { a0[o] = 0.f; a1[o] = 0.f; }
        #pragma unroll 16
        for (int c = 0; c < 64; ++c) {
            float xv0 = xb[c * 125 + lane];
            float xv1 = xb[c * 125 + 64 + l2];
            #pragma unroll
            for (int o = 0; o < 16; ++o) {
                float w = conv_s_w[o * 64 + c];      // wave-uniform -> s_load
                a0[o] += w * xv0;
                a1[o] += w * xv1;
            }
        }
        #pragma unroll
        for (int o = 0; o < 16; ++o) {
            sm[F_XS + o * 198 + 32 + lane] = a0[o];
            if (lane < 61) sm[F_XS + o * 198 + 96 + lane] = a1[o];
        }
    }

    // ---- fused BN constants + temporal taps (per-lane, oo = lane&15) ----
    const int oo = lane & 15, qg = lane >> 4, gg = oo >> 1;   // qg in 0..3
    float sa, cc;
    {
        float s1 = bn1_g[gg] * rsqrtf(bn1_v[gg] + 1e-5f);
        float b1 = (conv_t_b[gg] - bn1_m[gg]) * s1 + bn1_b[gg];
        float s2 = bn2_g[oo] * rsqrtf(bn2_v[oo] + 1e-5f);
        float ssum = 0.f;
        const float4* csw = reinterpret_cast<const float4*>(conv_s_w + oo * 64);
        #pragma unroll
        for (int i = 0; i < 16; ++i) {
            float4 v = csw[i];
            ssum += v.x + v.y + v.z + v.w;
        }
        sa = s1 * s2;
        cc = (b1 * ssum + conv_s_b[oo] - bn2_m[oo]) * s2 + bn2_b[oo];
    }
    float wt[63];
    #pragma unroll
    for (int k = 0; k < 63; ++k) wt[k] = conv_t_w[gg * 63 + k];

    WAVE_SYNC();   // stage-1 writes -> stage-2 reads (same wave, DS in-order)

    // ---- stage 2: temporal conv + BN + ELU + avg-pool ----
    // lane (oo,qg) produces pooled[oo][j], j = qg*7+jj (7,7,7,4 per group)
    #pragma unroll 1
    for (int jj = 0; jj < 7; ++jj) {
        int j  = qg * 7 + jj;
        int jc = min(j, 24);
        int base = F_XS + oo * 198 + 5 * jc + 1;
        float acc5[5] = {0.f, 0.f, 0.f, 0.f, 0.f};
        #pragma unroll
        for (int m = 0; m < 67; ++m) {
            float xv = sm[base + m];
            #pragma unroll
            for (int u = 0; u < 5; ++u)
                if (u <= m && m - u <= 62) acc5[u] += wt[m - u] * xv;
        }
        float psum = 0.f;
        #pragma unroll
        for (int u = 0; u < 5; ++u) {
            float v = acc5[u] * sa + cc;
            psum += (v > 0.f) ? v : (__expf(v) - 1.f);
        }
        if (j == jc) sm[F_PL + oo * 28 + j] = psum * 0.2f;
    }

    WAVE_SYNC();   // pooled writes -> proj reads

    // ---- stage 3: token projection (5,80)@(80,16)^T -> global TOK ----
    #pragma unroll
    for (int pass = 0; pass < 2; ++pass) {
        int oi = (pass == 0) ? lane : (64 + lane);
        int p = oi >> 4, dd = oi & 15;
        int pc = min(p, 4);
        bool act = (pass == 0) || (lane < 16);
        float acc = proj_b[dd];
        const float4* wp = reinterpret_cast<const float4*>(proj_w + dd * 80);
        #pragma unroll
        for (int i = 0; i < 20; ++i) {
            float4 w4 = wp[i];
            acc += w4.x * sm[F_PL + ((4*i+0)/5) * 28 + pc * 5 + ((4*i+0)%5)];
            acc += w4.y * sm[F_PL + ((4*i+1)/5) * 28 + pc * 5 + ((4*i+1)%5)];
            acc += w4.z * sm[F_PL + ((4*i+2)/5) * 28 + pc * 5 + ((4*i+2)%5)];
            acc += w4.w * sm[F_PL + ((4*i+3)/5) * 28 + pc * 5 + ((4*i+3)%5)];
        }
        if (act) tokws[b * 80 + pc * 16 + dd] = acc;
    }
}

// ===================== Kernel T: transformer + head ==========================
// Identical to round 7 (passed, absmax 0): 2 units x 128 thr; each unit
// processes 2 samples -> every LDS weight-row read feeds two FMA chains.
#define WQKV 0        // 192 rows x 20 (16 used)
#define BQKV 3840     // 192
#define WOUT 4032     // 16 rows x 68 (64 used)
#define BOUT 5120     // 16
#define WM1  5136     // 32 rows x 20
#define BM1  5776     // 32
#define WM2  5808     // 16 rows x 36 (32 used)
#define BM2  6384     // 16
#define LN1G 6400
#define LN1B 6416
#define LN2G 6432
#define LN2B 6448
#define WEND 6464
#define SSTR 1568     // per-sample scratch stride
#define SH1  0        // 6 x 20
#define SQKV 128      // 6 x 196 (q at +0 -> O after attention, k +64, v +128)
#define SMHS 1312     // 6 x 36
#define T_TOT (WEND + 4*SSTR)   // 12736 floats = 50.9 KB

extern "C" __global__ __launch_bounds__(256, 2)
void eegnet_transformer(
    const float* __restrict__ cls_token, const float* __restrict__ pe,
    const float* __restrict__ qkv_w, const float* __restrict__ qkv_b,
    const float* __restrict__ out_w, const float* __restrict__ out_b,
    const float* __restrict__ ln1_g, const float* __restrict__ ln1_b,
    const float* __restrict__ ln2_g, const float* __restrict__ ln2_b,
    const float* __restrict__ mlp_w1, const float* __restrict__ mlp_b1,
    const float* __restrict__ mlp_w2, const float* __restrict__ mlp_b2,
    const float* __restrict__ head_ln_g, const float* __restrict__ head_ln_b,
    const float* __restrict__ head_w, const float* __restrict__ head_b,
    const float* __restrict__ tokws, float* __restrict__ out)
{
    __shared__ __align__(16) float sm[T_TOT];
    const int tid = threadIdx.x;
    const int ss  = tid >> 7;              // unit (0/1)
    const int u   = tid & 127;
    const int sA  = blockIdx.x * 4 + ss * 2;   // two samples: sA, sA+1
    const int d16 = u & 15, qg = u >> 4;
    const int t6c = min(qg, 5);            // wave0: tokens 0-3; wave1: 4,5,5,5
    const int wav = u >> 6, al = u & 63;
    const int sbA = WEND + (ss * 2    ) * SSTR;
    const int sbB = WEND + (ss * 2 + 1) * SSTR;

    // z init (TOK from workspace; cls+pe from global)
    float zA, zB;
    {
        float peV = pe[t6c * 16 + d16];
        if (t6c == 0) {
            float cv = cls_token[d16];
            zA = cv + peV; zB = cv + peV;
        } else {
            zA = tokws[(sA    ) * 80 + (t6c - 1) * 16 + d16] + peV;
            zB = tokws[(sA + 1) * 80 + (t6c - 1) * 16 + d16] + peV;
        }
    }

    #pragma unroll 1
    for (int li = 0; li < 6; ++li) {
        __syncthreads();   // prev-layer reads done before restaging

        // --- stage layer weights into LDS (coalesced float4, 256 threads) ---
        {
            const float4* s1 = reinterpret_cast<const float4*>(qkv_w + li * 3072);
            #pragma unroll
            for (int it = 0; it < 3; ++it) {
                int i = tid + it * 256;
                float4 v = s1[i];
                int j = i >> 2, k = (i & 3) << 2;
                *reinterpret_cast<float4*>(&sm[WQKV + j * 20 + k]) = v;
            }
            {
                float4 v = reinterpret_cast<const float4*>(out_w + li * 1024)[tid];
                int j = tid >> 4, k = (tid & 15) << 2;
                *reinterpret_cast<float4*>(&sm[WOUT + j * 68 + k]) = v;
            }
            if (tid < 128) {
                float4 v = reinterpret_cast<const float4*>(mlp_w1 + li * 512)[tid];
                int j = tid >> 2, k = (tid & 3) << 2;
                *reinterpret_cast<float4*>(&sm[WM1 + j * 20 + k]) = v;
            } else {
                int i = tid - 128;
                float4 v = reinterpret_cast<const float4*>(mlp_w2 + li * 512)[i];
                int j = i >> 3, k = (i & 7) << 2;
                *reinterpret_cast<float4*>(&sm[WM2 + j * 36 + k]) = v;
            }
            if (tid < 192) sm[BQKV + tid] = qkv_b[li * 192 + tid];
            else if (tid < 208) sm[BOUT + tid - 192] = out_b[li * 16 + tid - 192];
            else if (tid < 240) sm[BM1 + tid - 208]  = mlp_b1[li * 32 + tid - 208];
            else               sm[BM2 + tid - 240]  = mlp_b2[li * 16 + tid - 240];
            if (tid >= 64 && tid < 80)        sm[LN1G + tid - 64]  = ln1_g[li * 16 + tid - 64];
            else if (tid >= 80 && tid < 96)   sm[LN1B + tid - 80]  = ln1_b[li * 16 + tid - 80];
            else if (tid >= 96 && tid < 112)  sm[LN2G + tid - 96]  = ln2_g[li * 16 + tid - 96];
            else if (tid >= 112 && tid < 128) sm[LN2B + tid - 112] = ln2_b[li * 16 + tid - 112];
        }
        __syncthreads();   // weights ready

        // --- LN1 -> H1 (both samples) ---
        {
            float g = sm[LN1G + d16], bb = sm[LN1B + d16];
            sm[sbA + SH1 + t6c * 20 + d16] = ln_norm16(zA, g, bb);
            sm[sbB + SH1 + t6c * 20 + d16] = ln_norm16(zB, g, bb);
        }
        WAVE_SYNC();

        float hrA[16], hrB[16];
        {
            const float4* pA = reinterpret_cast<const float4*>(&sm[sbA + SH1 + t6c * 20]);
            const float4* pB = reinterpret_cast<const float4*>(&sm[sbB + SH1 + t6c * 20]);
            #pragma unroll
            for (int i = 0; i < 4; ++i) {
                float4 va = pA[i], vb = pB[i];
                hrA[4*i+0]=va.x; hrA[4*i+1]=va.y; hrA[4*i+2]=va.z; hrA[4*i+3]=va.w;
                hrB[4*i+0]=vb.x; hrB[4*i+1]=vb.y; hrB[4*i+2]=vb.z; hrB[4*i+3]=vb.w;
            }
        }

        // --- qkv: weight row read once, two dot products ---
        #pragma unroll 2
        for (int r = 0; r < 12; ++r) {
            int j = d16 + 16 * r;
            const float4* wp = reinterpret_cast<const float4*>(&sm[WQKV + j * 20]);
            float4 w0 = wp[0], w1_ = wp[1], w2_ = wp[2], w3_ = wp[3];
            float bb = sm[BQKV + j];
            sm[sbA + SQKV + t6c * 196 + j] = bb + dot16(hrA, w0, w1_, w2_, w3_);
            sm[sbB + SQKV + t6c * 196 + j] = bb + dot16(hrB, w0, w1_, w2_, w3_);
        }
        __syncthreads();   // QKV ready (cross-wave K,V)

        // --- attention: wave0 -> queries 0-3 (32 lanes), wave1 -> 4,5 (16) ---
        {
            bool act = (wav == 0) ? (al < 32) : (al < 16);
            if (act) {
                int h  = al & 7;
                int qs = (wav == 0) ? (al >> 3) : 4 + (al >> 3);
                const int qoffA = sbA + SQKV + qs * 196 + h * 8;
                const int qoffB = sbB + SQKV + qs * 196 + h * 8;
                const float4* qpA = reinterpret_cast<const float4*>(&sm[qoffA]);
                const float4* qpB = reinterpret_cast<const float4*>(&sm[qoffB]);
                float4 qA0 = qpA[0], qA1 = qpA[1], qB0 = qpB[0], qB1 = qpB[1];
                float scA[6], scB[6];
                #pragma unroll
                for (int t = 0; t < 6; ++t) {
                    const float4* kA = reinterpret_cast<const float4*>(&sm[sbA + SQKV + t * 196 + 64 + h * 8]);
                    const float4* kB = reinterpret_cast<const float4*>(&sm[sbB + SQKV + t * 196 + 64 + h * 8]);
                    float4 a0 = kA[0], a1 = kA[1], b0 = kB[0], b1 = kB[1];
                    scA[t] = (qA0.x*a0.x + qA0.y*a0.y + qA0.z*a0.z + qA0.w*a0.w
                            + qA1.x*a1.x + qA1.y*a1.y + qA1.z*a1.z + qA1.w*a1.w)
                            * 0.35355339059327373f;
                    scB[t] = (qB0.x*b0.x + qB0.y*b0.y + qB0.z*b0.z + qB0.w*b0.w
                            + qB1.x*b1.x + qB1.y*b1.y + qB1.z*b1.z + qB1.w*b1.w)
                            * 0.35355339059327373f;
                }
                float mxA = scA[0], mxB = scB[0];
                #pragma unroll
                for (int t = 1; t < 6; ++t) { mxA = fmaxf(mxA, scA[t]); mxB = fmaxf(mxB, scB[t]); }
                float suA = 0.f, suB = 0.f;
                #pragma unroll
                for (int t = 0; t < 6; ++t) {
                    scA[t] = __expf(scA[t] - mxA); suA += scA[t];
                    scB[t] = __expf(scB[t] - mxB); suB += scB[t];
                }
                float ivA = 1.f / suA, ivB = 1.f / suB;
                float oA[8] = {0,0,0,0,0,0,0,0}, oB[8] = {0,0,0,0,0,0,0,0};
                #pragma unroll
                for (int t = 0; t < 6; ++t) {
                    const float4* vA = reinterpret_cast<const float4*>(&sm[sbA + SQKV + t * 196 + 128 + h * 8]);
                    const float4* vB = reinterpret_cast<const float4*>(&sm[sbB + SQKV + t * 196 + 128 + h * 8]);
                    float4 a0 = vA[0], a1 = vA[1], b0 = vB[0], b1 = vB[1];
                    float aa = scA[t] * ivA, ab = scB[t] * ivB;
                    oA[0]+=aa*a0.x; oA[1]+=aa*a0.y; oA[2]+=aa*a0.z; oA[3]+=aa*a0.w;
                    oA[4]+=aa*a1.x; oA[5]+=aa*a1.y; oA[6]+=aa*a1.z; oA[7]+=aa*a1.w;
                    oB[0]+=ab*b0.x; oB[1]+=ab*b0.y; oB[2]+=ab*b0.z; oB[3]+=ab*b0.w;
                    oB[4]+=ab*b1.x; oB[5]+=ab*b1.y; oB[6]+=ab*b1.z; oB[7]+=ab*b1.w;
                }
                *reinterpret_cast<float4*>(&sm[qoffA    ]) = float4{oA[0],oA[1],oA[2],oA[3]};
                *reinterpret_cast<float4*>(&sm[qoffA + 4]) = float4{oA[4],oA[5],oA[6],oA[7]};
                *reinterpret_cast<float4*>(&sm[qoffB    ]) = float4{oB[0],oB[1],oB[2],oB[3]};
                *reinterpret_cast<float4*>(&sm[qoffB + 4]) = float4{oB[4],oB[5],oB[6],oB[7]};
            }
        }
        WAVE_SYNC();   // O rows are wave-local (own wave computed own tokens)

        // --- out projection + residual (weight row once, two dots) ---
        {
            const float4* wop = reinterpret_cast<const float4*>(&sm[WOUT + d16 * 68]);
            const float4* oaA = reinterpret_cast<const float4*>(&sm[sbA + SQKV + t6c * 196]);
            const float4* oaB = reinterpret_cast<const float4*>(&sm[sbB + SQKV + t6c * 196]);
            float bb = sm[BOUT + d16];
            float aA = bb, aB = bb;
            #pragma unroll 4
            for (int i = 0; i < 16; ++i) {
                float4 w = wop[i];
                float4 va = oaA[i], vb = oaB[i];
                aA += va.x*w.x + va.y*w.y + va.z*w.z + va.w*w.w;
                aB += vb.x*w.x + vb.y*w.y + vb.z*w.z + vb.w*w.w;
            }
            zA += aA; zB += aB;
        }

        // --- LN2 -> H1 (both samples) ---
        {
            float g = sm[LN2G + d16], bb = sm[LN2B + d16];
            sm[sbA + SH1 + t6c * 20 + d16] = ln_norm16(zA, g, bb);
            sm[sbB + SH1 + t6c * 20 + d16] = ln_norm16(zB, g, bb);
        }
        WAVE_SYNC();
        {
            const float4* pA = reinterpret_cast<const float4*>(&sm[sbA + SH1 + t6c * 20]);
            const float4* pB = reinterpret_cast<const float4*>(&sm[sbB + SH1 + t6c * 20]);
            #pragma unroll
            for (int i = 0; i < 4; ++i) {
                float4 va = pA[i], vb = pB[i];
                hrA[4*i+0]=va.x; hrA[4*i+1]=va.y; hrA[4*i+2]=va.z; hrA[4*i+3]=va.w;
                hrB[4*i+0]=vb.x; hrB[4*i+1]=vb.y; hrB[4*i+2]=vb.z; hrB[4*i+3]=vb.w;
            }
        }

        // --- mlp1 + GELU -> MHS ---
        #pragma unroll
        for (int r = 0; r < 2; ++r) {
            int uu = d16 + 16 * r;
            const float4* wp = reinterpret_cast<const float4*>(&sm[WM1 + uu * 20]);
            float4 w0 = wp[0], w1_ = wp[1], w2_ = wp[2], w3_ = wp[3];
            float bb = sm[BM1 + uu];
            float aA = bb + dot16(hrA, w0, w1_, w2_, w3_);
            float aB = bb + dot16(hrB, w0, w1_, w2_, w3_);
            sm[sbA + SMHS + t6c * 36 + uu] = gelu_exact(aA);
            sm[sbB + SMHS + t6c * 36 + uu] = gelu_exact(aB);
        }
        WAVE_SYNC();

        // --- mlp2 + residual ---
        {
            const float4* wp = reinterpret_cast<const float4*>(&sm[WM2 + d16 * 36]);
            const float4* mA = reinterpret_cast<const float4*>(&sm[sbA + SMHS + t6c * 36]);
            const float4* mB = reinterpret_cast<const float4*>(&sm[sbB + SMHS + t6c * 36]);
            float bb = sm[BM2 + d16];
            float aA = bb, aB = bb;
            #pragma unroll
            for (int i = 0; i < 8; ++i) {
                float4 w = wp[i];
                float4 va = mA[i], vb = mB[i];
                aA += va.x*w.x + va.y*w.y + va.z*w.z + va.w*w.w;
                aB += vb.x*w.x + vb.y*w.y + vb.z*w.z + vb.w*w.w;
            }
            zA += aA; zB += aB;
        }
        // loop-top __syncthreads orders cross-wave reads before restaging
    }

    // ---------- head: LN(cls) -> 2-way linear -> softmax, both samples ----------
    if (u < 16) {
        float g = head_ln_g[d16], bb = head_ln_b[d16];
        float w0 = head_w[d16], w1 = head_w[16 + d16];
        float cvA = ln_norm16(zA, g, bb);
        float cvB = ln_norm16(zB, g, bb);
        float pA0 = cvA * w0, pA1 = cvA * w1;
        float pB0 = cvB * w0, pB1 = cvB * w1;
        #pragma unroll
        for (int off = 8; off >= 1; off >>= 1) {
            pA0 += __shfl_xor(pA0, off, 16);
            pA1 += __shfl_xor(pA1, off, 16);
            pB0 += __shfl_xor(pB0, off, 16);
            pB1 += __shfl_xor(pB1, off, 16);
        }
        if (u == 0) {
            float hb0 = head_b[0], hb1 = head_b[1];
            {
                float l0 = pA0 + hb0, l1 = pA1 + hb1;
                float mx = fmaxf(l0, l1);
                float e0 = __expf(l0 - mx), e1 = __expf(l1 - mx);
                float inv = 1.f / (e0 + e1);
                out[sA * 2 + 0] = e0 * inv;
                out[sA * 2 + 1] = e1 * inv;
            }
            {
                float l0 = pB0 + hb0, l1 = pB1 + hb1;
                float mx = fmaxf(l0, l1);
                float e0 = __expf(l0 - mx), e1 = __expf(l1 - mx);
                float inv = 1.f / (e0 + e1);
                out[(sA + 1) * 2 + 0] = e0 * inv;
                out[(sA + 1) * 2 + 1] = e1 * inv;
            }
        }
    }
}

extern "C" void kernel_launch(void* const* d_in, const int* in_sizes, int n_in,
                              void* d_out, int out_size, void* d_ws, size_t ws_size,
                              hipStream_t stream) {
    (void)n_in; (void)ws_size; (void)out_size;
    const float* a0  = (const float*)d_in[0];   // x
    const float* a1  = (const float*)d_in[1];   // conv_t_w
    const float* a2  = (const float*)d_in[2];   // conv_t_b
    const float* a3  = (const float*)d_in[3];   // bn1_g
    const float* a4  = (const float*)d_in[4];   // bn1_b
    const float* a5  = (const float*)d_in[5];   // bn1_m
    const float* a6  = (const float*)d_in[6];   // bn1_v
    const float* a7  = (const float*)d_in[7];   // conv_s_w
    const float* a8  = (const float*)d_in[8];   // conv_s_b
    const float* a9  = (const float*)d_in[9];   // bn2_g
    const float* a10 = (const float*)d_in[10];  // bn2_b
    const float* a11 = (const float*)d_in[11];  // bn2_m
    const float* a12 = (const float*)d_in[12];  // bn2_v
    const float* a13 = (const float*)d_in[13];  // proj_w
    const float* a14 = (const float*)d_in[14];  // proj_b
    const float* a15 = (const float*)d_in[15];  // cls_token
    const float* a16 = (const float*)d_in[16];  // pe
    const float* a17 = (const float*)d_in[17];  // qkv_w
    const float* a18 = (const float*)d_in[18];  // qkv_b
    const float* a19 = (const float*)d_in[19];  // out_w
    const float* a20 = (const float*)d_in[20];  // out_b
    const float* a21 = (const float*)d_in[21];  // ln1_g
    const float* a22 = (const float*)d_in[22];  // ln1_b
    const float* a23 = (const float*)d_in[23];  // ln2_g
    const float* a24 = (const float*)d_in[24];  // ln2_b
    const float* a25 = (const float*)d_in[25];  // mlp_w1
    const float* a26 = (const float*)d_in[26];  // mlp_b1
    const float* a27 = (const float*)d_in[27];  // mlp_w2
    const float* a28 = (const float*)d_in[28];  // mlp_b2
    const float* a29 = (const float*)d_in[29];  // head_ln_g
    const float* a30 = (const float*)d_in[30];  // head_ln_b
    const float* a31 = (const float*)d_in[31];  // head_w
    const float* a32 = (const float*)d_in[32];  // head_b

    int Bn = in_sizes[0] / (64 * 125);          // 2048
    float* tokws = (float*)d_ws;                // 2048 x 80 f32 = 640 KB

    eegnet_frontend<<<Bn, 64, 0, stream>>>(
        a0, a1, a2, a3, a4, a5, a6, a7, a8, a9, a10, a11, a12, a13, a14, tokws);

    eegnet_transformer<<<Bn / 4, 256, 0, stream>>>(
        a15, a16, a17, a18, a19, a20, a21, a22, a23, a24, a25, a26, a27, a28,
        a29, a30, a31, a32, tokws, (float*)d_out);
}

// Round 9
// 216.824 us; speedup vs baseline: 1.5107x; 1.0744x over previous
//
#include <hip/hip_runtime.h>

// Wave-synchronous fence: DS ops complete in order within a wave (ISA
// guarantee); this only stops the COMPILER from reordering/caching LDS.
#define WAVE_SYNC() do { asm volatile("" ::: "memory"); \
                         __builtin_amdgcn_wave_barrier(); \
                         asm volatile("" ::: "memory"); } while (0)

typedef _Float16 h2 __attribute__((ext_vector_type(2)));
typedef _Float16 h4 __attribute__((ext_vector_type(4)));
typedef _Float16 h8 __attribute__((ext_vector_type(8)));

__device__ __forceinline__ float fdot2(h2 a, h2 b, float c) {
#if defined(__has_builtin)
#if __has_builtin(__builtin_amdgcn_fdot2)
    return __builtin_amdgcn_fdot2(a, b, c, false);
#else
    return (float)a[0]*(float)b[0] + (float)a[1]*(float)b[1] + c;
#endif
#else
    return (float)a[0]*(float)b[0] + (float)a[1]*(float)b[1] + c;
#endif
}

__device__ __forceinline__ float dot8h(h8 a, h8 b, float c) {
    float s = c;
    #pragma unroll
    for (int i = 0; i < 4; ++i) {
        h2 x = {a[2*i], a[2*i+1]};
        h2 y = {b[2*i], b[2*i+1]};
        s = fdot2(x, y, s);
    }
    return s;
}

__device__ __forceinline__ float dot16h(h8 a0, h8 a1, h8 b0, h8 b1, float c) {
    return dot8h(a1, b1, dot8h(a0, b0, c));
}

__device__ __forceinline__ float ln_norm16(float z, float g, float bb) {
    float s = z, q = z * z;
    #pragma unroll
    for (int off = 8; off >= 1; off >>= 1) {
        s += __shfl_xor(s, off, 16);
        q += __shfl_xor(q, off, 16);
    }
    float mean = s * 0.0625f;
    float var  = q * 0.0625f - mean * mean;
    return (z - mean) * rsqrtf(var + 1e-5f) * g + bb;
}

__device__ __forceinline__ float gelu_exact(float a) {
    float xa = fabsf(a) * 0.70710678118654752f;
    float tt = 1.f / (1.f + 0.3275911f * xa);
    float poly = tt * (0.254829592f + tt * (-0.284496736f + tt * (1.421413741f
               + tt * (-1.453152027f + tt * 1.061405429f))));
    float erfv = 1.f - poly * __expf(-xa * xa);
    erfv = a >= 0.f ? erfv : -erfv;
    return 0.5f * a * (1.f + erfv);
}

// ========================= Kernel F: conv frontend ===========================
// 1 sample per 64-lane WAVE; zero __syncthreads (wave-local fences only).
#define F_XS  0       // 16 x 198 zero-padded
#define F_PL  3168    // 16 x 28
#define F_TOT 3616    // 14.5 KB

extern "C" __global__ __launch_bounds__(64, 2)
void eegnet_frontend(
    const float* __restrict__ x,
    const float* __restrict__ conv_t_w, const float* __restrict__ conv_t_b,
    const float* __restrict__ bn1_g, const float* __restrict__ bn1_b,
    const float* __restrict__ bn1_m, const float* __restrict__ bn1_v,
    const float* __restrict__ conv_s_w, const float* __restrict__ conv_s_b,
    const float* __restrict__ bn2_g, const float* __restrict__ bn2_b,
    const float* __restrict__ bn2_m, const float* __restrict__ bn2_v,
    const float* __restrict__ proj_w, const float* __restrict__ proj_b,
    float* __restrict__ tokws)
{
    __shared__ __align__(16) float sm[F_TOT];
    const int b    = blockIdx.x;
    const int lane = threadIdx.x;

    // zero ONLY the pad zones: per row [0,32) and [157,198) -> 73 per row
    for (int i = lane; i < 16 * 73; i += 64) {
        int row = i / 73, k = i - row * 73;
        int off = (k < 32) ? k : (k + 125);
        sm[F_XS + row * 198 + off] = 0.f;
    }

    // ---- stage 1: spatial conv; lane covers t=lane and t=64+lane ----
    {
        const float* xb = x + (size_t)b * 8000;
        const int l2 = min(lane, 60);
        float a0[16], a1[16];
        #pragma unroll
        for (int o = 0; o < 16; ++o) { a0[o] = 0.f; a1[o] = 0.f; }
        #pragma unroll 16
        for (int c = 0; c < 64; ++c) {
            float xv0 = xb[c * 125 + lane];
            float xv1 = xb[c * 125 + 64 + l2];
            #pragma unroll
            for (int o = 0; o < 16; ++o) {
                float w = conv_s_w[o * 64 + c];      // wave-uniform -> s_load
                a0[o] += w * xv0;
                a1[o] += w * xv1;
            }
        }
        #pragma unroll
        for (int o = 0; o < 16; ++o) {
            sm[F_XS + o * 198 + 32 + lane] = a0[o];
            if (lane < 61) sm[F_XS + o * 198 + 96 + lane] = a1[o];
        }
    }

    // ---- fused BN constants + temporal taps ----
    const int oo = lane & 15, qg = lane >> 4, gg = oo >> 1;
    float sa, cc;
    {
        float s1 = bn1_g[gg] * rsqrtf(bn1_v[gg] + 1e-5f);
        float b1 = (conv_t_b[gg] - bn1_m[gg]) * s1 + bn1_b[gg];
        float s2 = bn2_g[oo] * rsqrtf(bn2_v[oo] + 1e-5f);
        float ssum = 0.f;
        const float4* csw = reinterpret_cast<const float4*>(conv_s_w + oo * 64);
        #pragma unroll
        for (int i = 0; i < 16; ++i) {
            float4 v = csw[i];
            ssum += v.x + v.y + v.z + v.w;
        }
        sa = s1 * s2;
        cc = (b1 * ssum + conv_s_b[oo] - bn2_m[oo]) * s2 + bn2_b[oo];
    }
    float wt[63];
    #pragma unroll
    for (int k = 0; k < 63; ++k) wt[k] = conv_t_w[gg * 63 + k];

    WAVE_SYNC();

    // ---- stage 2: temporal conv + BN + ELU + avg-pool (unroll 2: 2 streams) ----
    #pragma unroll 2
    for (int jj = 0; jj < 7; ++jj) {
        int j  = qg * 7 + jj;
        int jc = min(j, 24);
        int base = F_XS + oo * 198 + 5 * jc + 1;
        float acc5[5] = {0.f, 0.f, 0.f, 0.f, 0.f};
        #pragma unroll
        for (int m = 0; m < 67; ++m) {
            float xv = sm[base + m];
            #pragma unroll
            for (int u = 0; u < 5; ++u)
                if (u <= m && m - u <= 62) acc5[u] += wt[m - u] * xv;
        }
        float psum = 0.f;
        #pragma unroll
        for (int u = 0; u < 5; ++u) {
            float v = acc5[u] * sa + cc;
            psum += (v > 0.f) ? v : (__expf(v) - 1.f);
        }
        if (j == jc) sm[F_PL + oo * 28 + j] = psum * 0.2f;
    }

    WAVE_SYNC();

    // ---- stage 3: token projection -> global TOK ----
    #pragma unroll
    for (int pass = 0; pass < 2; ++pass) {
        int oi = (pass == 0) ? lane : (64 + lane);
        int p = oi >> 4, dd = oi & 15;
        int pc = min(p, 4);
        bool act = (pass == 0) || (lane < 16);
        float acc = proj_b[dd];
        const float4* wp = reinterpret_cast<const float4*>(proj_w + dd * 80);
        #pragma unroll
        for (int i = 0; i < 20; ++i) {
            float4 w4 = wp[i];
            acc += w4.x * sm[F_PL + ((4*i+0)/5) * 28 + pc * 5 + ((4*i+0)%5)];
            acc += w4.y * sm[F_PL + ((4*i+1)/5) * 28 + pc * 5 + ((4*i+1)%5)];
            acc += w4.z * sm[F_PL + ((4*i+2)/5) * 28 + pc * 5 + ((4*i+2)%5)];
            acc += w4.w * sm[F_PL + ((4*i+3)/5) * 28 + pc * 5 + ((4*i+3)%5)];
        }
        if (act) tokws[b * 80 + pc * 16 + dd] = acc;
    }
}

// ===================== Kernel T: transformer + head (f16 operands) ===========
// Same structure as round 7/8 (passed); LDS matmul operands now _Float16,
// all accumulation fp32 via v_dot2_f32_f16. DS instr/wave/layer ~258 -> ~150.
//
// half-index offsets (byte = idx*2):
#define WQKVH 0          // 192 rows, stride 24 halfs (48 B, 16B-aligned rows)
#define WOUTH 4608       // 16 rows, stride 72
#define WM1H  5760       // 32 rows, stride 24
#define WM2H  6528       // 16 rows, stride 40   (ends half 7168 = byte 14336)
// float-index offsets into same LDS (byte = idx*4), after the half region:
#define BQKVF 3584       // 192
#define BOUTF 3776       // 16
#define BM1F  3792       // 32
#define BM2F  3824       // 16
#define LN1GF 3840
#define LN1BF 3856
#define LN2GF 3872
#define LN2BF 3888       // ends float 3904 = byte 15616
// per-sample scratch (half idx): base = SCR0 + sample*SSTRH
#define SCR0  7808
#define SSTRH 1584
#define SH1H  0          // 6 rows x stride 24
#define SQKVH 144        // 6 rows x stride 200 (q+0 -> O later, k+64, v+128)
#define SMHSH 1344       // 6 rows x stride 40
#define T_BYTES 28288    // 27.6 KB

extern "C" __global__ __launch_bounds__(256, 2)
void eegnet_transformer(
    const float* __restrict__ cls_token, const float* __restrict__ pe,
    const float* __restrict__ qkv_w, const float* __restrict__ qkv_b,
    const float* __restrict__ out_w, const float* __restrict__ out_b,
    const float* __restrict__ ln1_g, const float* __restrict__ ln1_b,
    const float* __restrict__ ln2_g, const float* __restrict__ ln2_b,
    const float* __restrict__ mlp_w1, const float* __restrict__ mlp_b1,
    const float* __restrict__ mlp_w2, const float* __restrict__ mlp_b2,
    const float* __restrict__ head_ln_g, const float* __restrict__ head_ln_b,
    const float* __restrict__ head_w, const float* __restrict__ head_b,
    const float* __restrict__ tokws, float* __restrict__ out)
{
    __shared__ __align__(16) unsigned char smb[T_BYTES];
    float*    smf = reinterpret_cast<float*>(smb);
    _Float16* smh = reinterpret_cast<_Float16*>(smb);

    const int tid = threadIdx.x;
    const int ss  = tid >> 7;              // unit (0/1)
    const int u   = tid & 127;
    const int sA  = blockIdx.x * 4 + ss * 2;
    const int d16 = u & 15, qg = u >> 4;
    const int t6c = min(qg, 5);            // wave0: tokens 0-3; wave1: 4,5,5,5
    const int wav = u >> 6, al = u & 63;
    const int sbA = SCR0 + (ss * 2    ) * SSTRH;
    const int sbB = SCR0 + (ss * 2 + 1) * SSTRH;

    // z init (fp32)
    float zA, zB;
    {
        float peV = pe[t6c * 16 + d16];
        if (t6c == 0) {
            float cv = cls_token[d16];
            zA = cv + peV; zB = cv + peV;
        } else {
            zA = tokws[(sA    ) * 80 + (t6c - 1) * 16 + d16] + peV;
            zB = tokws[(sA + 1) * 80 + (t6c - 1) * 16 + d16] + peV;
        }
    }

    #pragma unroll 1
    for (int li = 0; li < 6; ++li) {
        __syncthreads();   // prev-layer reads done before restaging

        // --- stage layer weights into LDS as f16 (coalesced float4 reads) ---
        {
            const float4* s1 = reinterpret_cast<const float4*>(qkv_w + li * 3072);
            #pragma unroll
            for (int it = 0; it < 3; ++it) {
                int i = tid + it * 256;
                float4 v = s1[i];
                int j = i >> 2, k = (i & 3) << 2;
                h4 hv = {(_Float16)v.x, (_Float16)v.y, (_Float16)v.z, (_Float16)v.w};
                *reinterpret_cast<h4*>(&smh[WQKVH + j * 24 + k]) = hv;
            }
            {
                float4 v = reinterpret_cast<const float4*>(out_w + li * 1024)[tid];
                int j = tid >> 4, k = (tid & 15) << 2;
                h4 hv = {(_Float16)v.x, (_Float16)v.y, (_Float16)v.z, (_Float16)v.w};
                *reinterpret_cast<h4*>(&smh[WOUTH + j * 72 + k]) = hv;
            }
            if (tid < 128) {
                float4 v = reinterpret_cast<const float4*>(mlp_w1 + li * 512)[tid];
                int j = tid >> 2, k = (tid & 3) << 2;
                h4 hv = {(_Float16)v.x, (_Float16)v.y, (_Float16)v.z, (_Float16)v.w};
                *reinterpret_cast<h4*>(&smh[WM1H + j * 24 + k]) = hv;
            } else {
                int i = tid - 128;
                float4 v = reinterpret_cast<const float4*>(mlp_w2 + li * 512)[i];
                int j = i >> 3, k = (i & 7) << 2;
                h4 hv = {(_Float16)v.x, (_Float16)v.y, (_Float16)v.z, (_Float16)v.w};
                *reinterpret_cast<h4*>(&smh[WM2H + j * 40 + k]) = hv;
            }
            if (tid < 192) smf[BQKVF + tid] = qkv_b[li * 192 + tid];
            else if (tid < 208) smf[BOUTF + tid - 192] = out_b[li * 16 + tid - 192];
            else if (tid < 240) smf[BM1F + tid - 208]  = mlp_b1[li * 32 + tid - 208];
            else               smf[BM2F + tid - 240]  = mlp_b2[li * 16 + tid - 240];
            if (tid >= 64 && tid < 80)        smf[LN1GF + tid - 64]  = ln1_g[li * 16 + tid - 64];
            else if (tid >= 80 && tid < 96)   smf[LN1BF + tid - 80]  = ln1_b[li * 16 + tid - 80];
            else if (tid >= 96 && tid < 112)  smf[LN2GF + tid - 96]  = ln2_g[li * 16 + tid - 96];
            else if (tid >= 112 && tid < 128) smf[LN2BF + tid - 112] = ln2_b[li * 16 + tid - 112];
        }
        __syncthreads();   // weights ready

        // --- LN1 -> H1 (f16, wave-local rows) ---
        {
            float g = smf[LN1GF + d16], bb = smf[LN1BF + d16];
            smh[sbA + SH1H + t6c * 24 + d16] = (_Float16)ln_norm16(zA, g, bb);
            smh[sbB + SH1H + t6c * 24 + d16] = (_Float16)ln_norm16(zB, g, bb);
        }
        WAVE_SYNC();

        h8 hA0 = *reinterpret_cast<const h8*>(&smh[sbA + SH1H + t6c * 24]);
        h8 hA1 = *reinterpret_cast<const h8*>(&smh[sbA + SH1H + t6c * 24 + 8]);
        h8 hB0 = *reinterpret_cast<const h8*>(&smh[sbB + SH1H + t6c * 24]);
        h8 hB1 = *reinterpret_cast<const h8*>(&smh[sbB + SH1H + t6c * 24 + 8]);

        // --- qkv: weight row (2 b128) read once, two fp32-accum dot16 ---
        #pragma unroll 2
        for (int r = 0; r < 12; ++r) {
            int j = d16 + 16 * r;
            h8 w0 = *reinterpret_cast<const h8*>(&smh[WQKVH + j * 24]);
            h8 w1 = *reinterpret_cast<const h8*>(&smh[WQKVH + j * 24 + 8]);
            float bb = smf[BQKVF + j];
            smh[sbA + SQKVH + t6c * 200 + j] = (_Float16)dot16h(hA0, hA1, w0, w1, bb);
            smh[sbB + SQKVH + t6c * 200 + j] = (_Float16)dot16h(hB0, hB1, w0, w1, bb);
        }
        __syncthreads();   // QKV ready (cross-wave K,V)

        // --- attention: wave0 -> queries 0-3 (32 lanes), wave1 -> 4,5 (16) ---
        {
            bool act = (wav == 0) ? (al < 32) : (al < 16);
            if (act) {
                int h  = al & 7;
                int qs = (wav == 0) ? (al >> 3) : 4 + (al >> 3);
                const int qoffA = sbA + SQKVH + qs * 200 + h * 8;
                const int qoffB = sbB + SQKVH + qs * 200 + h * 8;
                h8 qA = *reinterpret_cast<const h8*>(&smh[qoffA]);
                h8 qB = *reinterpret_cast<const h8*>(&smh[qoffB]);
                float scA[6], scB[6];
                #pragma unroll
                for (int t = 0; t < 6; ++t) {
                    h8 kA = *reinterpret_cast<const h8*>(&smh[sbA + SQKVH + t * 200 + 64 + h * 8]);
                    h8 kB = *reinterpret_cast<const h8*>(&smh[sbB + SQKVH + t * 200 + 64 + h * 8]);
                    scA[t] = dot8h(qA, kA, 0.f) * 0.35355339059327373f;
                    scB[t] = dot8h(qB, kB, 0.f) * 0.35355339059327373f;
                }
                float mxA = scA[0], mxB = scB[0];
                #pragma unroll
                for (int t = 1; t < 6; ++t) { mxA = fmaxf(mxA, scA[t]); mxB = fmaxf(mxB, scB[t]); }
                float suA = 0.f, suB = 0.f;
                #pragma unroll
                for (int t = 0; t < 6; ++t) {
                    scA[t] = __expf(scA[t] - mxA); suA += scA[t];
                    scB[t] = __expf(scB[t] - mxB); suB += scB[t];
                }
                float ivA = 1.f / suA, ivB = 1.f / suB;
                // O accumulated in packed f16 (6 terms, O(1) values -> ~1e-3 err)
                h2 oA[4], oB[4];
                #pragma unroll
                for (int k2 = 0; k2 < 4; ++k2) { oA[k2] = h2{0, 0}; oB[k2] = h2{0, 0}; }
                #pragma unroll
                for (int t = 0; t < 6; ++t) {
                    h8 vA = *reinterpret_cast<const h8*>(&smh[sbA + SQKVH + t * 200 + 128 + h * 8]);
                    h8 vB = *reinterpret_cast<const h8*>(&smh[sbB + SQKVH + t * 200 + 128 + h * 8]);
                    _Float16 aa = (_Float16)(scA[t] * ivA);
                    _Float16 ab = (_Float16)(scB[t] * ivB);
                    h2 av = {aa, aa}, bv = {ab, ab};
                    #pragma unroll
                    for (int k2 = 0; k2 < 4; ++k2) {
                        h2 va = {vA[2*k2], vA[2*k2+1]};
                        h2 vb = {vB[2*k2], vB[2*k2+1]};
                        oA[k2] += av * va;
                        oB[k2] += bv * vb;
                    }
                }
                h8 stA, stB;
                #pragma unroll
                for (int k2 = 0; k2 < 4; ++k2) {
                    stA[2*k2] = oA[k2][0]; stA[2*k2+1] = oA[k2][1];
                    stB[2*k2] = oB[k2][0]; stB[2*k2+1] = oB[k2][1];
                }
                *reinterpret_cast<h8*>(&smh[qoffA]) = stA;   // overwrite own q slot
                *reinterpret_cast<h8*>(&smh[qoffB]) = stB;
            }
        }
        WAVE_SYNC();   // O rows are wave-local

        // --- out projection + residual ---
        {
            float aA = smf[BOUTF + d16], aB = aA;
            #pragma unroll
            for (int i = 0; i < 8; ++i) {
                h8 w  = *reinterpret_cast<const h8*>(&smh[WOUTH + d16 * 72 + 8 * i]);
                h8 va = *reinterpret_cast<const h8*>(&smh[sbA + SQKVH + t6c * 200 + 8 * i]);
                h8 vb = *reinterpret_cast<const h8*>(&smh[sbB + SQKVH + t6c * 200 + 8 * i]);
                aA = dot8h(va, w, aA);
                aB = dot8h(vb, w, aB);
            }
            zA += aA; zB += aB;
        }

        // --- LN2 -> H1 ---
        {
            float g = smf[LN2GF + d16], bb = smf[LN2BF + d16];
            smh[sbA + SH1H + t6c * 24 + d16] = (_Float16)ln_norm16(zA, g, bb);
            smh[sbB + SH1H + t6c * 24 + d16] = (_Float16)ln_norm16(zB, g, bb);
        }
        WAVE_SYNC();
        hA0 = *reinterpret_cast<const h8*>(&smh[sbA + SH1H + t6c * 24]);
        hA1 = *reinterpret_cast<const h8*>(&smh[sbA + SH1H + t6c * 24 + 8]);
        hB0 = *reinterpret_cast<const h8*>(&smh[sbB + SH1H + t6c * 24]);
        hB1 = *reinterpret_cast<const h8*>(&smh[sbB + SH1H + t6c * 24 + 8]);

        // --- mlp1 + GELU -> MHS (f16) ---
        #pragma unroll
        for (int r = 0; r < 2; ++r) {
            int uu = d16 + 16 * r;
            h8 w0 = *reinterpret_cast<const h8*>(&smh[WM1H + uu * 24]);
            h8 w1 = *reinterpret_cast<const h8*>(&smh[WM1H + uu * 24 + 8]);
            float bb = smf[BM1F + uu];
            float aA = dot16h(hA0, hA1, w0, w1, bb);
            float aB = dot16h(hB0, hB1, w0, w1, bb);
            smh[sbA + SMHSH + t6c * 40 + uu] = (_Float16)gelu_exact(aA);
            smh[sbB + SMHSH + t6c * 40 + uu] = (_Float16)gelu_exact(aB);
        }
        WAVE_SYNC();

        // --- mlp2 + residual ---
        {
            float aA = smf[BM2F + d16], aB = aA;
            #pragma unroll
            for (int i = 0; i < 4; ++i) {
                h8 w  = *reinterpret_cast<const h8*>(&smh[WM2H + d16 * 40 + 8 * i]);
                h8 va = *reinterpret_cast<const h8*>(&smh[sbA + SMHSH + t6c * 40 + 8 * i]);
                h8 vb = *reinterpret_cast<const h8*>(&smh[sbB + SMHSH + t6c * 40 + 8 * i]);
                aA = dot8h(va, w, aA);
                aB = dot8h(vb, w, aB);
            }
            zA += aA; zB += aB;
        }
        // loop-top __syncthreads orders cross-wave reads before restaging
    }

    // ---------- head: fp32 LN(cls) -> 2-way linear -> softmax ----------
    if (u < 16) {
        float g = head_ln_g[d16], bb = head_ln_b[d16];
        float w0 = head_w[d16], w1 = head_w[16 + d16];
        float cvA = ln_norm16(zA, g, bb);
        float cvB = ln_norm16(zB, g, bb);
        float pA0 = cvA * w0, pA1 = cvA * w1;
        float pB0 = cvB * w0, pB1 = cvB * w1;
        #pragma unroll
        for (int off = 8; off >= 1; off >>= 1) {
            pA0 += __shfl_xor(pA0, off, 16);
            pA1 += __shfl_xor(pA1, off, 16);
            pB0 += __shfl_xor(pB0, off, 16);
            pB1 += __shfl_xor(pB1, off, 16);
        }
        if (u == 0) {
            float hb0 = head_b[0], hb1 = head_b[1];
            {
                float l0 = pA0 + hb0, l1 = pA1 + hb1;
                float mx = fmaxf(l0, l1);
                float e0 = __expf(l0 - mx), e1 = __expf(l1 - mx);
                float inv = 1.f / (e0 + e1);
                out[sA * 2 + 0] = e0 * inv;
                out[sA * 2 + 1] = e1 * inv;
            }
            {
                float l0 = pB0 + hb0, l1 = pB1 + hb1;
                float mx = fmaxf(l0, l1);
                float e0 = __expf(l0 - mx), e1 = __expf(l1 - mx);
                float inv = 1.f / (e0 + e1);
                out[(sA + 1) * 2 + 0] = e0 * inv;
                out[(sA + 1) * 2 + 1] = e1 * inv;
            }
        }
    }
}

extern "C" void kernel_launch(void* const* d_in, const int* in_sizes, int n_in,
                              void* d_out, int out_size, void* d_ws, size_t ws_size,
                              hipStream_t stream) {
    (void)n_in; (void)ws_size; (void)out_size;
    const float* a0  = (const float*)d_in[0];   // x
    const float* a1  = (const float*)d_in[1];   // conv_t_w
    const float* a2  = (const float*)d_in[2];   // conv_t_b
    const float* a3  = (const float*)d_in[3];   // bn1_g
    const float* a4  = (const float*)d_in[4];   // bn1_b
    const float* a5  = (const float*)d_in[5];   // bn1_m
    const float* a6  = (const float*)d_in[6];   // bn1_v
    const float* a7  = (const float*)d_in[7];   // conv_s_w
    const float* a8  = (const float*)d_in[8];   // conv_s_b
    const float* a9  = (const float*)d_in[9];   // bn2_g
    const float* a10 = (const float*)d_in[10];  // bn2_b
    const float* a11 = (const float*)d_in[11];  // bn2_m
    const float* a12 = (const float*)d_in[12];  // bn2_v
    const float* a13 = (const float*)d_in[13];  // proj_w
    const float* a14 = (const float*)d_in[14];  // proj_b
    const float* a15 = (const float*)d_in[15];  // cls_token
    const float* a16 = (const float*)d_in[16];  // pe
    const float* a17 = (const float*)d_in[17];  // qkv_w
    const float* a18 = (const float*)d_in[18];  // qkv_b
    const float* a19 = (const float*)d_in[19];  // out_w
    const float* a20 = (const float*)d_in[20];  // out_b
    const float* a21 = (const float*)d_in[21];  // ln1_g
    const float* a22 = (const float*)d_in[22];  // ln1_b
    const float* a23 = (const float*)d_in[23];  // ln2_g
    const float* a24 = (const float*)d_in[24];  // ln2_b
    const float* a25 = (const float*)d_in[25];  // mlp_w1
    const float* a26 = (const float*)d_in[26];  // mlp_b1
    const float* a27 = (const float*)d_in[27];  // mlp_w2
    const float* a28 = (const float*)d_in[28];  // mlp_b2
    const float* a29 = (const float*)d_in[29];  // head_ln_g
    const float* a30 = (const float*)d_in[30];  // head_ln_b
    const float* a31 = (const float*)d_in[31];  // head_w
    const float* a32 = (const float*)d_in[32];  // head_b

    int Bn = in_sizes[0] / (64 * 125);          // 2048
    float* tokws = (float*)d_ws;                // 2048 x 80 f32 = 640 KB

    eegnet_frontend<<<Bn, 64, 0, stream>>>(
        a0, a1, a2, a3, a4, a5, a6, a7, a8, a9, a10, a11, a12, a13, a14, tokws);

    eegnet_transformer<<<Bn / 4, 256, 0, stream>>>(
        a15, a16, a17, a18, a19, a20, a21, a22, a23, a24, a25, a26, a27, a28,
        a29, a30, a31, a32, tokws, (float*)d_out);
}

// Round 10
// 214.316 us; speedup vs baseline: 1.5283x; 1.0117x over previous
//
#include <hip/hip_runtime.h>

// Wave-synchronous fence: DS ops complete in order within a wave (ISA
// guarantee); this only stops the COMPILER from reordering/caching LDS.
#define WAVE_SYNC() do { asm volatile("" ::: "memory"); \
                         __builtin_amdgcn_wave_barrier(); \
                         asm volatile("" ::: "memory"); } while (0)

typedef _Float16 h2 __attribute__((ext_vector_type(2)));
typedef _Float16 h4 __attribute__((ext_vector_type(4)));
typedef _Float16 h8 __attribute__((ext_vector_type(8)));

__device__ __forceinline__ float fdot2(h2 a, h2 b, float c) {
#if defined(__has_builtin)
#if __has_builtin(__builtin_amdgcn_fdot2)
    return __builtin_amdgcn_fdot2(a, b, c, false);
#else
    return (float)a[0]*(float)b[0] + (float)a[1]*(float)b[1] + c;
#endif
#else
    return (float)a[0]*(float)b[0] + (float)a[1]*(float)b[1] + c;
#endif
}

__device__ __forceinline__ float dot8h(h8 a, h8 b, float c) {
    float s = c;
    #pragma unroll
    for (int i = 0; i < 4; ++i) {
        h2 x = {a[2*i], a[2*i+1]};
        h2 y = {b[2*i], b[2*i+1]};
        s = fdot2(x, y, s);
    }
    return s;
}

__device__ __forceinline__ float dot16h(h8 a0, h8 a1, h8 b0, h8 b1, float c) {
    return dot8h(a1, b1, dot8h(a0, b0, c));
}

__device__ __forceinline__ float ln_norm16(float z, float g, float bb) {
    float s = z, q = z * z;
    #pragma unroll
    for (int off = 8; off >= 1; off >>= 1) {
        s += __shfl_xor(s, off, 16);
        q += __shfl_xor(q, off, 16);
    }
    float mean = s * 0.0625f;
    float var  = q * 0.0625f - mean * mean;
    return (z - mean) * rsqrtf(var + 1e-5f) * g + bb;
}

__device__ __forceinline__ float gelu_exact(float a) {
    float xa = fabsf(a) * 0.70710678118654752f;
    float tt = 1.f / (1.f + 0.3275911f * xa);
    float poly = tt * (0.254829592f + tt * (-0.284496736f + tt * (1.421413741f
               + tt * (-1.453152027f + tt * 1.061405429f))));
    float erfv = 1.f - poly * __expf(-xa * xa);
    erfv = a >= 0.f ? erfv : -erfv;
    return 0.5f * a * (1.f + erfv);
}

// ========================= Kernel F: conv frontend ===========================
// 1 sample per 64-lane WAVE; zero __syncthreads.
// Stage 0: 32 coalesced 16B-aligned float4 loads -> f16 LDS ring XR (16 KB).
//   (4x bytes-in-flight vs round 9's scalar gathers -> MLP-limited BW up ~4x.)
// Stage 1: reads XR columns via ds_read_u16 (imm offsets, 2-way banks = free),
//   f32 accumulate. XSP (f32, stride 204) ALIASES XR: safe because every XR
//   read feeds the accumulators and thus retires before the first XSP write
//   in wave-lockstep program order (pad-zeroing also moved after the reads).
#define F_XSTR 204         // XSP row stride (float4-aligned rows; banks <=2-way)
#define F_PL   4000        // float idx 4000 = byte 16000, above XR's 16000 B
#define F_TOT  4448        // 17.8 KB -> 8 blocks/CU (142 KB of 160)

extern "C" __global__ __launch_bounds__(64, 2)
void eegnet_frontend(
    const float* __restrict__ x,
    const float* __restrict__ conv_t_w, const float* __restrict__ conv_t_b,
    const float* __restrict__ bn1_g, const float* __restrict__ bn1_b,
    const float* __restrict__ bn1_m, const float* __restrict__ bn1_v,
    const float* __restrict__ conv_s_w, const float* __restrict__ conv_s_b,
    const float* __restrict__ bn2_g, const float* __restrict__ bn2_b,
    const float* __restrict__ bn2_m, const float* __restrict__ bn2_v,
    const float* __restrict__ proj_w, const float* __restrict__ proj_b,
    float* __restrict__ tokws)
{
    __shared__ __align__(16) float sm[F_TOT];
    _Float16* xr = reinterpret_cast<_Float16*>(sm);
    const int b    = blockIdx.x;
    const int lane = threadIdx.x;

    // ---- stage 0: x -> LDS as f16 (linear ring, coalesced float4) ----
    {
        const float4* xb4 = reinterpret_cast<const float4*>(x + (size_t)b * 8000);
        #pragma unroll
        for (int k = 0; k < 32; ++k) {
            int g = min(k * 64 + lane, 1999);     // tail lanes dup (same value)
            float4 v = xb4[g];
            h4 hv = {(_Float16)v.x, (_Float16)v.y, (_Float16)v.z, (_Float16)v.w};
            *reinterpret_cast<h4*>(&xr[4 * g]) = hv;   // 8B-aligned ds_write_b64
        }
    }
    WAVE_SYNC();   // XR writes -> XR reads (same wave, DS in-order)

    // ---- stage 1: spatial conv from XR columns; then write XSP (aliases XR) --
    {
        const int l2 = min(lane, 60);
        float a0[16], a1[16];
        #pragma unroll
        for (int o = 0; o < 16; ++o) { a0[o] = 0.f; a1[o] = 0.f; }
        #pragma unroll 8
        for (int c = 0; c < 64; ++c) {
            float xv0 = (float)xr[c * 125 + lane];       // ds_read_u16 imm 250c
            float xv1 = (float)xr[c * 125 + 64 + l2];
            #pragma unroll
            for (int o = 0; o < 16; ++o) {
                float w = conv_s_w[o * 64 + c];          // wave-uniform -> s_load
                a0[o] += w * xv0;
                a1[o] += w * xv1;
            }
        }
        WAVE_SYNC();   // all XR reads retired before aliased XSP writes

        // zero pad zones now (they alias XR): per row [0,32) and [157,204)
        for (int i = lane; i < 16 * 79; i += 64) {
            int row = i / 79, k = i - row * 79;
            int off = (k < 32) ? k : (k + 125);
            sm[row * F_XSTR + off] = 0.f;
        }
        #pragma unroll
        for (int o = 0; o < 16; ++o) {
            sm[o * F_XSTR + 32 + lane] = a0[o];
            if (lane < 61) sm[o * F_XSTR + 96 + lane] = a1[o];
        }
    }

    // ---- fused BN constants + temporal taps ----
    const int oo = lane & 15, qg = lane >> 4, gg = oo >> 1;
    float sa, cc;
    {
        float s1 = bn1_g[gg] * rsqrtf(bn1_v[gg] + 1e-5f);
        float b1 = (conv_t_b[gg] - bn1_m[gg]) * s1 + bn1_b[gg];
        float s2 = bn2_g[oo] * rsqrtf(bn2_v[oo] + 1e-5f);
        float ssum = 0.f;
        const float4* csw = reinterpret_cast<const float4*>(conv_s_w + oo * 64);
        #pragma unroll
        for (int i = 0; i < 16; ++i) {
            float4 v = csw[i];
            ssum += v.x + v.y + v.z + v.w;
        }
        sa = s1 * s2;
        cc = (b1 * ssum + conv_s_b[oo] - bn2_m[oo]) * s2 + bn2_b[oo];
    }
    float wt[63];
    #pragma unroll
    for (int k = 0; k < 63; ++k) wt[k] = conv_t_w[gg * 63 + k];

    WAVE_SYNC();

    // ---- stage 2: temporal conv + BN + ELU + avg-pool ----
    #pragma unroll 2
    for (int jj = 0; jj < 7; ++jj) {
        int j  = qg * 7 + jj;
        int jc = min(j, 24);
        int base = oo * F_XSTR + 5 * jc + 1;
        float acc5[5] = {0.f, 0.f, 0.f, 0.f, 0.f};
        #pragma unroll
        for (int m = 0; m < 67; ++m) {
            float xv = sm[base + m];
            #pragma unroll
            for (int u = 0; u < 5; ++u)
                if (u <= m && m - u <= 62) acc5[u] += wt[m - u] * xv;
        }
        float psum = 0.f;
        #pragma unroll
        for (int u = 0; u < 5; ++u) {
            float v = acc5[u] * sa + cc;
            psum += (v > 0.f) ? v : (__expf(v) - 1.f);
        }
        if (j == jc) sm[F_PL + oo * 28 + j] = psum * 0.2f;
    }

    WAVE_SYNC();

    // ---- stage 3: token projection -> global TOK ----
    #pragma unroll
    for (int pass = 0; pass < 2; ++pass) {
        int oi = (pass == 0) ? lane : (64 + lane);
        int p = oi >> 4, dd = oi & 15;
        int pc = min(p, 4);
        bool act = (pass == 0) || (lane < 16);
        float acc = proj_b[dd];
        const float4* wp = reinterpret_cast<const float4*>(proj_w + dd * 80);
        #pragma unroll
        for (int i = 0; i < 20; ++i) {
            float4 w4 = wp[i];
            acc += w4.x * sm[F_PL + ((4*i+0)/5) * 28 + pc * 5 + ((4*i+0)%5)];
            acc += w4.y * sm[F_PL + ((4*i+1)/5) * 28 + pc * 5 + ((4*i+1)%5)];
            acc += w4.z * sm[F_PL + ((4*i+2)/5) * 28 + pc * 5 + ((4*i+2)%5)];
            acc += w4.w * sm[F_PL + ((4*i+3)/5) * 28 + pc * 5 + ((4*i+3)%5)];
        }
        if (act) tokws[b * 80 + pc * 16 + dd] = acc;
    }
}

// ===================== Kernel T: transformer + head (f16 operands) ===========
// Identical to round 9 (passed, absmax 3.9e-3).
#define WQKVH 0          // 192 rows, stride 24 halfs
#define WOUTH 4608       // 16 rows, stride 72
#define WM1H  5760       // 32 rows, stride 24
#define WM2H  6528       // 16 rows, stride 40
#define BQKVF 3584       // float idx
#define BOUTF 3776
#define BM1F  3792
#define BM2F  3824
#define LN1GF 3840
#define LN1BF 3856
#define LN2GF 3872
#define LN2BF 3888
#define SCR0  7808       // half idx
#define SSTRH 1584
#define SH1H  0
#define SQKVH 144
#define SMHSH 1344
#define T_BYTES 28288

extern "C" __global__ __launch_bounds__(256, 2)
void eegnet_transformer(
    const float* __restrict__ cls_token, const float* __restrict__ pe,
    const float* __restrict__ qkv_w, const float* __restrict__ qkv_b,
    const float* __restrict__ out_w, const float* __restrict__ out_b,
    const float* __restrict__ ln1_g, const float* __restrict__ ln1_b,
    const float* __restrict__ ln2_g, const float* __restrict__ ln2_b,
    const float* __restrict__ mlp_w1, const float* __restrict__ mlp_b1,
    const float* __restrict__ mlp_w2, const float* __restrict__ mlp_b2,
    const float* __restrict__ head_ln_g, const float* __restrict__ head_ln_b,
    const float* __restrict__ head_w, const float* __restrict__ head_b,
    const float* __restrict__ tokws, float* __restrict__ out)
{
    __shared__ __align__(16) unsigned char smb[T_BYTES];
    float*    smf = reinterpret_cast<float*>(smb);
    _Float16* smh = reinterpret_cast<_Float16*>(smb);

    const int tid = threadIdx.x;
    const int ss  = tid >> 7;
    const int u   = tid & 127;
    const int sA  = blockIdx.x * 4 + ss * 2;
    const int d16 = u & 15, qg = u >> 4;
    const int t6c = min(qg, 5);
    const int wav = u >> 6, al = u & 63;
    const int sbA = SCR0 + (ss * 2    ) * SSTRH;
    const int sbB = SCR0 + (ss * 2 + 1) * SSTRH;

    float zA, zB;
    {
        float peV = pe[t6c * 16 + d16];
        if (t6c == 0) {
            float cv = cls_token[d16];
            zA = cv + peV; zB = cv + peV;
        } else {
            zA = tokws[(sA    ) * 80 + (t6c - 1) * 16 + d16] + peV;
            zB = tokws[(sA + 1) * 80 + (t6c - 1) * 16 + d16] + peV;
        }
    }

    #pragma unroll 1
    for (int li = 0; li < 6; ++li) {
        __syncthreads();

        {
            const float4* s1 = reinterpret_cast<const float4*>(qkv_w + li * 3072);
            #pragma unroll
            for (int it = 0; it < 3; ++it) {
                int i = tid + it * 256;
                float4 v = s1[i];
                int j = i >> 2, k = (i & 3) << 2;
                h4 hv = {(_Float16)v.x, (_Float16)v.y, (_Float16)v.z, (_Float16)v.w};
                *reinterpret_cast<h4*>(&smh[WQKVH + j * 24 + k]) = hv;
            }
            {
                float4 v = reinterpret_cast<const float4*>(out_w + li * 1024)[tid];
                int j = tid >> 4, k = (tid & 15) << 2;
                h4 hv = {(_Float16)v.x, (_Float16)v.y, (_Float16)v.z, (_Float16)v.w};
                *reinterpret_cast<h4*>(&smh[WOUTH + j * 72 + k]) = hv;
            }
            if (tid < 128) {
                float4 v = reinterpret_cast<const float4*>(mlp_w1 + li * 512)[tid];
                int j = tid >> 2, k = (tid & 3) << 2;
                h4 hv = {(_Float16)v.x, (_Float16)v.y, (_Float16)v.z, (_Float16)v.w};
                *reinterpret_cast<h4*>(&smh[WM1H + j * 24 + k]) = hv;
            } else {
                int i = tid - 128;
                float4 v = reinterpret_cast<const float4*>(mlp_w2 + li * 512)[i];
                int j = i >> 3, k = (i & 7) << 2;
                h4 hv = {(_Float16)v.x, (_Float16)v.y, (_Float16)v.z, (_Float16)v.w};
                *reinterpret_cast<h4*>(&smh[WM2H + j * 40 + k]) = hv;
            }
            if (tid < 192) smf[BQKVF + tid] = qkv_b[li * 192 + tid];
            else if (tid < 208) smf[BOUTF + tid - 192] = out_b[li * 16 + tid - 192];
            else if (tid < 240) smf[BM1F + tid - 208]  = mlp_b1[li * 32 + tid - 208];
            else               smf[BM2F + tid - 240]  = mlp_b2[li * 16 + tid - 240];
            if (tid >= 64 && tid < 80)        smf[LN1GF + tid - 64]  = ln1_g[li * 16 + tid - 64];
            else if (tid >= 80 && tid < 96)   smf[LN1BF + tid - 80]  = ln1_b[li * 16 + tid - 80];
            else if (tid >= 96 && tid < 112)  smf[LN2GF + tid - 96]  = ln2_g[li * 16 + tid - 96];
            else if (tid >= 112 && tid < 128) smf[LN2BF + tid - 112] = ln2_b[li * 16 + tid - 112];
        }
        __syncthreads();

        {
            float g = smf[LN1GF + d16], bb = smf[LN1BF + d16];
            smh[sbA + SH1H + t6c * 24 + d16] = (_Float16)ln_norm16(zA, g, bb);
            smh[sbB + SH1H + t6c * 24 + d16] = (_Float16)ln_norm16(zB, g, bb);
        }
        WAVE_SYNC();

        h8 hA0 = *reinterpret_cast<const h8*>(&smh[sbA + SH1H + t6c * 24]);
        h8 hA1 = *reinterpret_cast<const h8*>(&smh[sbA + SH1H + t6c * 24 + 8]);
        h8 hB0 = *reinterpret_cast<const h8*>(&smh[sbB + SH1H + t6c * 24]);
        h8 hB1 = *reinterpret_cast<const h8*>(&smh[sbB + SH1H + t6c * 24 + 8]);

        #pragma unroll 2
        for (int r = 0; r < 12; ++r) {
            int j = d16 + 16 * r;
            h8 w0 = *reinterpret_cast<const h8*>(&smh[WQKVH + j * 24]);
            h8 w1 = *reinterpret_cast<const h8*>(&smh[WQKVH + j * 24 + 8]);
            float bb = smf[BQKVF + j];
            smh[sbA + SQKVH + t6c * 200 + j] = (_Float16)dot16h(hA0, hA1, w0, w1, bb);
            smh[sbB + SQKVH + t6c * 200 + j] = (_Float16)dot16h(hB0, hB1, w0, w1, bb);
        }
        __syncthreads();

        {
            bool act = (wav == 0) ? (al < 32) : (al < 16);
            if (act) {
                int h  = al & 7;
                int qs = (wav == 0) ? (al >> 3) : 4 + (al >> 3);
                const int qoffA = sbA + SQKVH + qs * 200 + h * 8;
                const int qoffB = sbB + SQKVH + qs * 200 + h * 8;
                h8 qA = *reinterpret_cast<const h8*>(&smh[qoffA]);
                h8 qB = *reinterpret_cast<const h8*>(&smh[qoffB]);
                float scA[6], scB[6];
                #pragma unroll
                for (int t = 0; t < 6; ++t) {
                    h8 kA = *reinterpret_cast<const h8*>(&smh[sbA + SQKVH + t * 200 + 64 + h * 8]);
                    h8 kB = *reinterpret_cast<const h8*>(&smh[sbB + SQKVH + t * 200 + 64 + h * 8]);
                    scA[t] = dot8h(qA, kA, 0.f) * 0.35355339059327373f;
                    scB[t] = dot8h(qB, kB, 0.f) * 0.35355339059327373f;
                }
                float mxA = scA[0], mxB = scB[0];
                #pragma unroll
                for (int t = 1; t < 6; ++t) { mxA = fmaxf(mxA, scA[t]); mxB = fmaxf(mxB, scB[t]); }
                float suA = 0.f, suB = 0.f;
                #pragma unroll
                for (int t = 0; t < 6; ++t) {
                    scA[t] = __expf(scA[t] - mxA); suA += scA[t];
                    scB[t] = __expf(scB[t] - mxB); suB += scB[t];
                }
                float ivA = 1.f / suA, ivB = 1.f / suB;
                h2 oA[4], oB[4];
                #pragma unroll
                for (int k2 = 0; k2 < 4; ++k2) { oA[k2] = h2{0, 0}; oB[k2] = h2{0, 0}; }
                #pragma unroll
                for (int t = 0; t < 6; ++t) {
                    h8 vA = *reinterpret_cast<const h8*>(&smh[sbA + SQKVH + t * 200 + 128 + h * 8]);
                    h8 vB = *reinterpret_cast<const h8*>(&smh[sbB + SQKVH + t * 200 + 128 + h * 8]);
                    _Float16 aa = (_Float16)(scA[t] * ivA);
                    _Float16 ab = (_Float16)(scB[t] * ivB);
                    h2 av = {aa, aa}, bv = {ab, ab};
                    #pragma unroll
                    for (int k2 = 0; k2 < 4; ++k2) {
                        h2 va = {vA[2*k2], vA[2*k2+1]};
                        h2 vb = {vB[2*k2], vB[2*k2+1]};
                        oA[k2] += av * va;
                        oB[k2] += bv * vb;
                    }
                }
                h8 stA, stB;
                #pragma unroll
                for (int k2 = 0; k2 < 4; ++k2) {
                    stA[2*k2] = oA[k2][0]; stA[2*k2+1] = oA[k2][1];
                    stB[2*k2] = oB[k2][0]; stB[2*k2+1] = oB[k2][1];
                }
                *reinterpret_cast<h8*>(&smh[qoffA]) = stA;
                *reinterpret_cast<h8*>(&smh[qoffB]) = stB;
            }
        }
        WAVE_SYNC();

        {
            float aA = smf[BOUTF + d16], aB = aA;
            #pragma unroll
            for (int i = 0; i < 8; ++i) {
                h8 w  = *reinterpret_cast<const h8*>(&smh[WOUTH + d16 * 72 + 8 * i]);
                h8 va = *reinterpret_cast<const h8*>(&smh[sbA + SQKVH + t6c * 200 + 8 * i]);
                h8 vb = *reinterpret_cast<const h8*>(&smh[sbB + SQKVH + t6c * 200 + 8 * i]);
                aA = dot8h(va, w, aA);
                aB = dot8h(vb, w, aB);
            }
            zA += aA; zB += aB;
        }

        {
            float g = smf[LN2GF + d16], bb = smf[LN2BF + d16];
            smh[sbA + SH1H + t6c * 24 + d16] = (_Float16)ln_norm16(zA, g, bb);
            smh[sbB + SH1H + t6c * 24 + d16] = (_Float16)ln_norm16(zB, g, bb);
        }
        WAVE_SYNC();
        hA0 = *reinterpret_cast<const h8*>(&smh[sbA + SH1H + t6c * 24]);
        hA1 = *reinterpret_cast<const h8*>(&smh[sbA + SH1H + t6c * 24 + 8]);
        hB0 = *reinterpret_cast<const h8*>(&smh[sbB + SH1H + t6c * 24]);
        hB1 = *reinterpret_cast<const h8*>(&smh[sbB + SH1H + t6c * 24 + 8]);

        #pragma unroll
        for (int r = 0; r < 2; ++r) {
            int uu = d16 + 16 * r;
            h8 w0 = *reinterpret_cast<const h8*>(&smh[WM1H + uu * 24]);
            h8 w1 = *reinterpret_cast<const h8*>(&smh[WM1H + uu * 24 + 8]);
            float bb = smf[BM1F + uu];
            float aA = dot16h(hA0, hA1, w0, w1, bb);
            float aB = dot16h(hB0, hB1, w0, w1, bb);
            smh[sbA + SMHSH + t6c * 40 + uu] = (_Float16)gelu_exact(aA);
            smh[sbB + SMHSH + t6c * 40 + uu] = (_Float16)gelu_exact(aB);
        }
        WAVE_SYNC();

        {
            float aA = smf[BM2F + d16], aB = aA;
            #pragma unroll
            for (int i = 0; i < 4; ++i) {
                h8 w  = *reinterpret_cast<const h8*>(&smh[WM2H + d16 * 40 + 8 * i]);
                h8 va = *reinterpret_cast<const h8*>(&smh[sbA + SMHSH + t6c * 40 + 8 * i]);
                h8 vb = *reinterpret_cast<const h8*>(&smh[sbB + SMHSH + t6c * 40 + 8 * i]);
                aA = dot8h(va, w, aA);
                aB = dot8h(vb, w, aB);
            }
            zA += aA; zB += aB;
        }
    }

    if (u < 16) {
        float g = head_ln_g[d16], bb = head_ln_b[d16];
        float w0 = head_w[d16], w1 = head_w[16 + d16];
        float cvA = ln_norm16(zA, g, bb);
        float cvB = ln_norm16(zB, g, bb);
        float pA0 = cvA * w0, pA1 = cvA * w1;
        float pB0 = cvB * w0, pB1 = cvB * w1;
        #pragma unroll
        for (int off = 8; off >= 1; off >>= 1) {
            pA0 += __shfl_xor(pA0, off, 16);
            pA1 += __shfl_xor(pA1, off, 16);
            pB0 += __shfl_xor(pB0, off, 16);
            pB1 += __shfl_xor(pB1, off, 16);
        }
        if (u == 0) {
            float hb0 = head_b[0], hb1 = head_b[1];
            {
                float l0 = pA0 + hb0, l1 = pA1 + hb1;
                float mx = fmaxf(l0, l1);
                float e0 = __expf(l0 - mx), e1 = __expf(l1 - mx);
                float inv = 1.f / (e0 + e1);
                out[sA * 2 + 0] = e0 * inv;
                out[sA * 2 + 1] = e1 * inv;
            }
            {
                float l0 = pB0 + hb0, l1 = pB1 + hb1;
                float mx = fmaxf(l0, l1);
                float e0 = __expf(l0 - mx), e1 = __expf(l1 - mx);
                float inv = 1.f / (e0 + e1);
                out[(sA + 1) * 2 + 0] = e0 * inv;
                out[(sA + 1) * 2 + 1] = e1 * inv;
            }
        }
    }
}

extern "C" void kernel_launch(void* const* d_in, const int* in_sizes, int n_in,
                              void* d_out, int out_size, void* d_ws, size_t ws_size,
                              hipStream_t stream) {
    (void)n_in; (void)ws_size; (void)out_size;
    const float* a0  = (const float*)d_in[0];   // x
    const float* a1  = (const float*)d_in[1];   // conv_t_w
    const float* a2  = (const float*)d_in[2];   // conv_t_b
    const float* a3  = (const float*)d_in[3];   // bn1_g
    const float* a4  = (const float*)d_in[4];   // bn1_b
    const float* a5  = (const float*)d_in[5];   // bn1_m
    const float* a6  = (const float*)d_in[6];   // bn1_v
    const float* a7  = (const float*)d_in[7];   // conv_s_w
    const float* a8  = (const float*)d_in[8];   // conv_s_b
    const float* a9  = (const float*)d_in[9];   // bn2_g
    const float* a10 = (const float*)d_in[10];  // bn2_b
    const float* a11 = (const float*)d_in[11];  // bn2_m
    const float* a12 = (const float*)d_in[12];  // bn2_v
    const float* a13 = (const float*)d_in[13];  // proj_w
    const float* a14 = (const float*)d_in[14];  // proj_b
    const float* a15 = (const float*)d_in[15];  // cls_token
    const float* a16 = (const float*)d_in[16];  // pe
    const float* a17 = (const float*)d_in[17];  // qkv_w
    const float* a18 = (const float*)d_in[18];  // qkv_b
    const float* a19 = (const float*)d_in[19];  // out_w
    const float* a20 = (const float*)d_in[20];  // out_b
    const float* a21 = (const float*)d_in[21];  // ln1_g
    const float* a22 = (const float*)d_in[22];  // ln1_b
    const float* a23 = (const float*)d_in[23];  // ln2_g
    const float* a24 = (const float*)d_in[24];  // ln2_b
    const float* a25 = (const float*)d_in[25];  // mlp_w1
    const float* a26 = (const float*)d_in[26];  // mlp_b1
    const float* a27 = (const float*)d_in[27];  // mlp_w2
    const float* a28 = (const float*)d_in[28];  // mlp_b2
    const float* a29 = (const float*)d_in[29];  // head_ln_g
    const float* a30 = (const float*)d_in[30];  // head_ln_b
    const float* a31 = (const float*)d_in[31];  // head_w
    const float* a32 = (const float*)d_in[32];  // head_b

    int Bn = in_sizes[0] / (64 * 125);          // 2048
    float* tokws = (float*)d_ws;                // 2048 x 80 f32 = 640 KB

    eegnet_frontend<<<Bn, 64, 0, stream>>>(
        a0, a1, a2, a3, a4, a5, a6, a7, a8, a9, a10, a11, a12, a13, a14, tokws);

    eegnet_transformer<<<Bn / 4, 256, 0, stream>>>(
        a15, a16, a17, a18, a19, a20, a21, a22, a23, a24, a25, a26, a27, a28,
        a29, a30, a31, a32, tokws, (float*)d_out);
}